// Round 2
// baseline (623.508 us; speedup 1.0000x reference)
//
#include <hip/hip_runtime.h>

// ICNN_net_1503238553972 — round 20: BARRIER-FREE fhat.
// R19 lesson: occupancy 39->62% made it WORSE (237->408us fused) — the
// stall is block-lockstep barriers + per-row overhead, not residency.
// New fhat: each wave owns 32 rows end-to-end, wave-private 8KB LDS H
// slice, acc[8][2] (all 128 outs per wave). Inter-layer transpose is
// wave-local LDS -> only lgkmcnt waits, ZERO __syncthreads in the fused
// kernel. f1 and ff converted to MFMA (padded-K and 2-row A resp.).
// vnet restored to the proven R18 ILP-2 form (wave-private arenas,
// already barrier-free). LDS 32KB/block, launch_bounds(256,4).

typedef _Float16 v2h __attribute__((ext_vector_type(2)));
typedef __fp16   v2hf __attribute__((ext_vector_type(2)));
typedef _Float16 v4h __attribute__((ext_vector_type(4)));
typedef _Float16 v8h __attribute__((ext_vector_type(8)));
typedef float    v4f __attribute__((ext_vector_type(4)));

__device__ __forceinline__ v2h cvt_pk(float a, float b){
  v2hf r = __builtin_amdgcn_cvt_pkrtz(a, b);
  union { v2hf f; v2h h; } u; u.f = r;
  return u.h;
}

#define NPTS 500000
#define FH_BLK  ((NPTS + 127) / 128)   // 3907
#define FUSED_GRID (FH_BLK * 2)        // 7814 (even=fhat, odd=vnet)

// offsets in halves inside g_w16
#define OFF_FW    0               // f2..f5: L*16384, [o*128+k]
#define OFF_V2Z   65536           // [j*64+k]
#define OFF_V3Z   69632
#define OFF_V2ZT  73728           // [k*64+j]
#define OFF_V3ZT  77824
#define OFF_VL1T  81920           // [c*64+j]
#define OFF_V2XT  82048
#define OFF_V3XT  82176
#define OFF_VFZ   82304           // [64]
#define OFF_FFW   82368           // [c*128+k]
#define OFF_F1W   82624           // [oc*2+c] (kept: ff junk A-rows read here)
#define OFF_F1P   82880           // f1 padded [o*32+k], k<2 valid else 0
#define W16_DATA  86976
#define W16_TOTAL (W16_DATA + 2048)   // zero pad: junk A-rows stay in-bounds

__device__ __align__(16) _Float16 g_w16[W16_TOTAL];
__device__ __align__(16) float    g_fh[NPTS * 2];   // f_hat per row (fp32)
__device__ __align__(16) float4   g_grad[NPTS];     // (g0, g1, V, pad)

#if defined(__has_builtin)
#if __has_builtin(__builtin_amdgcn_fdot2)
#define FDOT2(a,b,c) __builtin_amdgcn_fdot2((a),(b),(c),false)
#endif
#endif
#ifndef FDOT2
__device__ __forceinline__ float fdot2_fb(v2h a, v2h b, float c){
  return fmaf((float)a.x, (float)b.x, fmaf((float)a.y, (float)b.y, c));
}
#define FDOT2(a,b,c) fdot2_fb((a),(b),(c))
#endif

__device__ __forceinline__ float srelu(float x){
  float c = fminf(fmaxf(x, 0.f), 1.f);
  return c * fmaf(-0.5f, c, x);
}
__device__ __forceinline__ float sreluD(float x){
  return fminf(fmaxf(x, 0.f), 1.f);
}
__device__ __forceinline__ float sreluD_from_z(float z){
  return fminf(sqrtf(2.f * z), 1.f);
}

// ---- packed f16 activations (2 f32 in -> 2 f16 out) ----
__device__ __forceinline__ v2h lrelu_pk(float a, float b){
  v2h x = cvt_pk(a, b);
  v2h m = x * (v2h){(_Float16)0.01f, (_Float16)0.01f};
  return __builtin_elementwise_max(x, m);
}
__device__ __forceinline__ v2h srelu_pk(float a, float b){
  v2h x = cvt_pk(a, b);
  const v2h z0 = (v2h){(_Float16)0.f, (_Float16)0.f};
  const v2h o1 = (v2h){(_Float16)1.f, (_Float16)1.f};
  const v2h hf = (v2h){(_Float16)0.5f, (_Float16)0.5f};
  v2h c = __builtin_elementwise_min(__builtin_elementwise_max(x, z0), o1);
  v2h t = x - c * hf;
  return c * t;
}

// ---------------- prep: fp32 weights -> f16 layouts (+zero pad) ----------------
__global__ __launch_bounds__(256) void prep_kernel(
  const float* __restrict__ f2w, const float* __restrict__ f3w,
  const float* __restrict__ f4w, const float* __restrict__ f5w,
  const float* __restrict__ V2z, const float* __restrict__ V3z,
  const float* __restrict__ Vl1, const float* __restrict__ V2x,
  const float* __restrict__ V3x, const float* __restrict__ Vfz,
  const float* __restrict__ ffw, const float* __restrict__ f1w)
{
  const int i = blockIdx.x * 256 + threadIdx.x;
  if (i >= W16_TOTAL) return;
  if (i >= W16_DATA){ g_w16[i] = (_Float16)0.f; return; }
  float v;
  if (i < 65536){
    const float* W[4] = {f2w, f3w, f4w, f5w};
    v = W[i >> 14][i & 16383];
  } else if (i < 69632)  v = V2z[i - 65536];
  else if (i < 73728)    v = V3z[i - 69632];
  else if (i < 77824){ int r = i - 73728; v = V2z[(r & 63)*64 + (r >> 6)]; }
  else if (i < 81920){ int r = i - 77824; v = V3z[(r & 63)*64 + (r >> 6)]; }
  else if (i < 82048){ int r = i - 81920; v = Vl1[(r & 63)*2 + (r >> 6)]; }
  else if (i < 82176){ int r = i - 82048; v = V2x[(r & 63)*2 + (r >> 6)]; }
  else if (i < 82304){ int r = i - 82176; v = V3x[(r & 63)*2 + (r >> 6)]; }
  else if (i < 82368)    v = Vfz[i - 82304];
  else if (i < 82624)    v = ffw[i - 82368];
  else if (i < 82880)    v = f1w[i - 82624];
  else { int r = i - 82880; int k = r & 31; v = (k < 2) ? f1w[(r >> 5)*2 + k] : 0.f; }
  g_w16[i] = (_Float16)v;
}

// ================= fhat: wave-private, barrier-free =================
// One wave owns 32 data rows; Hw = wave-private 32x128 f16 (8 KB).
// Layer: h' = W @ h, in place over Hw. A = W rows from g_w16 (L1/L2-hot),
// B = Hw columns (XOR-swizzled b128 reads). No __syncthreads anywhere.
__device__ __forceinline__ void fh_layer_w(_Float16* Hw,
    const _Float16* __restrict__ Wl, const float* __restrict__ Bp,
    int lm, int q)
{
  v4f acc[8][2];
#pragma unroll
  for (int mt = 0; mt < 8; ++mt){
    acc[mt][0] = (v4f){0.f,0.f,0.f,0.f};
    acc[mt][1] = (v4f){0.f,0.f,0.f,0.f};
  }
#pragma unroll
  for (int kt = 0; kt < 4; ++kt){
    const int sw = ((kt*4 + q) ^ lm) << 3;
    v8h B0 = *(const v8h*)(Hw + lm*128 + sw);
    v8h B1 = *(const v8h*)(Hw + (16 + lm)*128 + sw);
#pragma unroll
    for (int mt = 0; mt < 8; ++mt){
      v8h A = *(const v8h*)(Wl + (mt*16 + lm)*128 + kt*32 + q*8);
      acc[mt][0] = __builtin_amdgcn_mfma_f32_16x16x32_f16(A, B0, acc[mt][0], 0,0,0);
      acc[mt][1] = __builtin_amdgcn_mfma_f32_16x16x32_f16(A, B1, acc[mt][1], 0,0,0);
    }
  }
  // epilogue: bias + lrelu, write back in place (data-dep orders after reads)
#pragma unroll
  for (int mt = 0; mt < 8; ++mt){
    const int o0 = mt*16 + q*4;
    const v4f bv = *(const v4f*)(Bp + o0);
    const int coff = (((o0 >> 3) ^ lm) << 3) + (o0 & 7);
    v4h h0, h1;
    *(v2h*)&h0       = lrelu_pk(acc[mt][0][0] + bv[0], acc[mt][0][1] + bv[1]);
    *((v2h*)&h0 + 1) = lrelu_pk(acc[mt][0][2] + bv[2], acc[mt][0][3] + bv[3]);
    *(v2h*)&h1       = lrelu_pk(acc[mt][1][0] + bv[0], acc[mt][1][1] + bv[1]);
    *((v2h*)&h1 + 1) = lrelu_pk(acc[mt][1][2] + bv[2], acc[mt][1][3] + bv[3]);
    *(v4h*)(Hw + lm*128 + coff)        = h0;
    *(v4h*)(Hw + (16 + lm)*128 + coff) = h1;
  }
}

__device__ __forceinline__ void fhat_body(int b, char* smem,
  const float* __restrict__ X,
  const float* __restrict__ f1b, const float* __restrict__ f2b,
  const float* __restrict__ f3b, const float* __restrict__ f4b,
  const float* __restrict__ f5b, const float* __restrict__ ffb)
{
  const int t  = threadIdx.x;
  const int w  = t >> 6;
  const int l  = t & 63;
  const int lm = l & 15;
  const int q  = l >> 4;
  _Float16* const Hw = (_Float16*)smem + w*4096;   // 8 KB per wave
  const int row0 = b*128 + w*32;

  // ---- f1 via MFMA: A = f1w padded to K=32, B = x in registers ----
  {
    int r0 = row0 + lm;      if (r0 > NPTS-1) r0 = NPTS-1;
    int r1 = row0 + 16 + lm; if (r1 > NPTS-1) r1 = NPTS-1;
    const float2 x0 = *(const float2*)(X + r0*2);
    const float2 x1 = *(const float2*)(X + r1*2);
    v8h Bx0 = (v8h){(_Float16)0.f,(_Float16)0.f,(_Float16)0.f,(_Float16)0.f,
                    (_Float16)0.f,(_Float16)0.f,(_Float16)0.f,(_Float16)0.f};
    v8h Bx1 = Bx0;
    if (q == 0){
      Bx0[0] = (_Float16)x0.x; Bx0[1] = (_Float16)x0.y;
      Bx1[0] = (_Float16)x1.x; Bx1[1] = (_Float16)x1.y;
    }
    v4f acc[8][2];
#pragma unroll
    for (int mt = 0; mt < 8; ++mt){
      acc[mt][0] = (v4f){0.f,0.f,0.f,0.f};
      acc[mt][1] = (v4f){0.f,0.f,0.f,0.f};
    }
#pragma unroll
    for (int mt = 0; mt < 8; ++mt){
      v8h A = *(const v8h*)(g_w16 + OFF_F1P + (mt*16 + lm)*32 + q*8);
      acc[mt][0] = __builtin_amdgcn_mfma_f32_16x16x32_f16(A, Bx0, acc[mt][0], 0,0,0);
      acc[mt][1] = __builtin_amdgcn_mfma_f32_16x16x32_f16(A, Bx1, acc[mt][1], 0,0,0);
    }
#pragma unroll
    for (int mt = 0; mt < 8; ++mt){
      const int o0 = mt*16 + q*4;
      const v4f bv = *(const v4f*)(f1b + o0);
      const int coff = (((o0 >> 3) ^ lm) << 3) + (o0 & 7);
      v4h h0, h1;
      *(v2h*)&h0       = lrelu_pk(acc[mt][0][0] + bv[0], acc[mt][0][1] + bv[1]);
      *((v2h*)&h0 + 1) = lrelu_pk(acc[mt][0][2] + bv[2], acc[mt][0][3] + bv[3]);
      *(v2h*)&h1       = lrelu_pk(acc[mt][1][0] + bv[0], acc[mt][1][1] + bv[1]);
      *((v2h*)&h1 + 1) = lrelu_pk(acc[mt][1][2] + bv[2], acc[mt][1][3] + bv[3]);
      *(v4h*)(Hw + lm*128 + coff)        = h0;
      *(v4h*)(Hw + (16 + lm)*128 + coff) = h1;
    }
  }

  fh_layer_w(Hw, g_w16 + OFF_FW,         f2b, lm, q);
  fh_layer_w(Hw, g_w16 + OFF_FW + 16384, f3b, lm, q);
  fh_layer_w(Hw, g_w16 + OFF_FW + 32768, f4b, lm, q);
  fh_layer_w(Hw, g_w16 + OFF_FW + 49152, f5b, lm, q);

  // ---- ff via MFMA: A rows 0,1 = ffw (junk rows in-bounds, ignored) ----
  {
    v4f a0 = (v4f){0.f,0.f,0.f,0.f};
    v4f a1 = (v4f){0.f,0.f,0.f,0.f};
#pragma unroll
    for (int kt = 0; kt < 4; ++kt){
      const int sw = ((kt*4 + q) ^ lm) << 3;
      v8h A  = *(const v8h*)(g_w16 + OFF_FFW + lm*128 + kt*32 + q*8);
      v8h B0 = *(const v8h*)(Hw + lm*128 + sw);
      v8h B1 = *(const v8h*)(Hw + (16 + lm)*128 + sw);
      a0 = __builtin_amdgcn_mfma_f32_16x16x32_f16(A, B0, a0, 0,0,0);
      a1 = __builtin_amdgcn_mfma_f32_16x16x32_f16(A, B1, a1, 0,0,0);
    }
    if (q == 0){
      const float fb0 = ffb[0], fb1 = ffb[1];
      const int r0 = row0 + lm, r1 = row0 + 16 + lm;
      if (r0 < NPTS) *(float2*)(g_fh + r0*2) = make_float2(a0[0] + fb0, a0[1] + fb1);
      if (r1 < NPTS) *(float2*)(g_fh + r1*2) = make_float2(a1[0] + fb0, a1[1] + fb1);
    }
  }
}

// ================= vnet: R18 ILP-2, 2 arenas/pipeline (barrier-free) =================
__device__ __forceinline__ void vfwd2_l2(_Float16* zoutA, _Float16* zoutB,
    const _Float16* __restrict__ Wz,   // V2Z [o][k]
    const _Float16* __restrict__ WxT,  // V2XT [2][64]
    const _Float16* __restrict__ Wl1T, // VL1T [2][64]
    float dA0, float dA1, float dB0, float dB1, int lm, int q)
{
  v4f accA[4], accB[4];
#pragma unroll
  for (int mt = 0; mt < 4; ++mt){
    accA[mt] = (v4f){0.f,0.f,0.f,0.f};
    accB[mt] = (v4f){0.f,0.f,0.f,0.f};
  }
  const int rs = lm & 7;
#pragma unroll
  for (int kt = 0; kt < 2; ++kt){
    v8h w0 = *(const v8h*)(Wl1T + kt*32 + q*8);
    v8h w1 = *(const v8h*)(Wl1T + 64 + kt*32 + q*8);
    v8h BA, BB;
#pragma unroll
    for (int j2 = 0; j2 < 4; ++j2){
      const float a0 = (float)w0[2*j2  ], a1 = (float)w0[2*j2+1];
      const float c0 = (float)w1[2*j2  ], c1 = (float)w1[2*j2+1];
      ((v2h*)&BA)[j2] = srelu_pk(fmaf(dA0,a0,dA1*c0), fmaf(dA0,a1,dA1*c1));
      ((v2h*)&BB)[j2] = srelu_pk(fmaf(dB0,a0,dB1*c0), fmaf(dB0,a1,dB1*c1));
    }
#pragma unroll
    for (int mt = 0; mt < 4; ++mt){
      v8h A = *(const v8h*)(Wz + (mt*16 + lm)*64 + kt*32 + q*8);
      accA[mt] = __builtin_amdgcn_mfma_f32_16x16x32_f16(A, BA, accA[mt], 0,0,0);
      accB[mt] = __builtin_amdgcn_mfma_f32_16x16x32_f16(A, BB, accB[mt], 0,0,0);
    }
  }
#pragma unroll
  for (int mt = 0; mt < 4; ++mt){
    const int o0 = mt*16 + q*4;
    const int off = (((o0 >> 3) ^ rs) << 3) + (o0 & 7);
    float vA[4], vB[4];
#pragma unroll
    for (int reg = 0; reg < 4; ++reg){
      const float wx0 = (float)WxT[o0 + reg];
      const float wx1 = (float)WxT[64 + o0 + reg];
      vA[reg] = accA[mt][reg] + wx0*dA0 + wx1*dA1;
      vB[reg] = accB[mt][reg] + wx0*dB0 + wx1*dB1;
    }
    v4h hA, hB;
    *(v2h*)&hA       = srelu_pk(vA[0], vA[1]);
    *((v2h*)&hA + 1) = srelu_pk(vA[2], vA[3]);
    *(v2h*)&hB       = srelu_pk(vB[0], vB[1]);
    *((v2h*)&hB + 1) = srelu_pk(vB[2], vB[3]);
    *(v4h*)(zoutA + lm*64 + off) = hA;
    *(v4h*)(zoutB + lm*64 + off) = hB;
  }
}

__device__ __forceinline__ void vfwd2(const _Float16* zinA, _Float16* zoutA,
    const _Float16* zinB, _Float16* zoutB,
    const _Float16* __restrict__ Wz, const _Float16* __restrict__ WxT,
    float dA0, float dA1, float dB0, float dB1, int lm, int q)
{
  v4f accA[4], accB[4];
#pragma unroll
  for (int mt = 0; mt < 4; ++mt){
    accA[mt] = (v4f){0.f,0.f,0.f,0.f};
    accB[mt] = (v4f){0.f,0.f,0.f,0.f};
  }
  const int rs = lm & 7;
#pragma unroll
  for (int kt = 0; kt < 2; ++kt){
    const int sw = (((kt*4 + q) ^ rs) << 3);
    v8h BA = *(const v8h*)(zinA + lm*64 + sw);
    v8h BB = *(const v8h*)(zinB + lm*64 + sw);
#pragma unroll
    for (int mt = 0; mt < 4; ++mt){
      v8h A = *(const v8h*)(Wz + (mt*16 + lm)*64 + kt*32 + q*8);
      accA[mt] = __builtin_amdgcn_mfma_f32_16x16x32_f16(A, BA, accA[mt], 0,0,0);
      accB[mt] = __builtin_amdgcn_mfma_f32_16x16x32_f16(A, BB, accB[mt], 0,0,0);
    }
  }
#pragma unroll
  for (int mt = 0; mt < 4; ++mt){
    const int o0 = mt*16 + q*4;
    const int off = (((o0 >> 3) ^ rs) << 3) + (o0 & 7);
    float vA[4], vB[4];
#pragma unroll
    for (int reg = 0; reg < 4; ++reg){
      const float wx0 = (float)WxT[o0 + reg];
      const float wx1 = (float)WxT[64 + o0 + reg];
      vA[reg] = accA[mt][reg] + wx0*dA0 + wx1*dA1;
      vB[reg] = accB[mt][reg] + wx0*dB0 + wx1*dB1;
    }
    v4h hA, hB;
    *(v2h*)&hA       = srelu_pk(vA[0], vA[1]);
    *((v2h*)&hA + 1) = srelu_pk(vA[2], vA[3]);
    *(v2h*)&hB       = srelu_pk(vB[0], vB[1]);
    *((v2h*)&hB + 1) = srelu_pk(vB[2], vB[3]);
    *(v4h*)(zoutA + lm*64 + off) = hA;
    *(v4h*)(zoutB + lm*64 + off) = hB;
  }
}

__device__ __forceinline__ void vbwd2(const _Float16* ginA, _Float16* zioA,
    const _Float16* ginB, _Float16* zioB,
    const _Float16* __restrict__ WT, int lm, int q)
{
  v4f accA[4], accB[4];
#pragma unroll
  for (int mt = 0; mt < 4; ++mt){
    accA[mt] = (v4f){0.f,0.f,0.f,0.f};
    accB[mt] = (v4f){0.f,0.f,0.f,0.f};
  }
  const int rs = lm & 7;
#pragma unroll
  for (int kt = 0; kt < 2; ++kt){
    const int sw = (((kt*4 + q) ^ rs) << 3);
    v8h BA = *(const v8h*)(ginA + lm*64 + sw);
    v8h BB = *(const v8h*)(ginB + lm*64 + sw);
#pragma unroll
    for (int mt = 0; mt < 4; ++mt){
      v8h A = *(const v8h*)(WT + (mt*16 + lm)*64 + kt*32 + q*8);
      accA[mt] = __builtin_amdgcn_mfma_f32_16x16x32_f16(A, BA, accA[mt], 0,0,0);
      accB[mt] = __builtin_amdgcn_mfma_f32_16x16x32_f16(A, BB, accB[mt], 0,0,0);
    }
  }
#pragma unroll
  for (int mt = 0; mt < 4; ++mt){
    const int k0 = mt*16 + q*4;
    const int off = (((k0 >> 3) ^ rs) << 3) + (k0 & 7);
    _Float16* pA = zioA + lm*64 + off;
    _Float16* pB = zioB + lm*64 + off;
    v4h zA = *(const v4h*)pA;
    v4h zB = *(const v4h*)pB;
    float sA0 = accA[mt][0] * sreluD_from_z((float)zA[0]);
    float sA1 = accA[mt][1] * sreluD_from_z((float)zA[1]);
    float sA2 = accA[mt][2] * sreluD_from_z((float)zA[2]);
    float sA3 = accA[mt][3] * sreluD_from_z((float)zA[3]);
    float sB0 = accB[mt][0] * sreluD_from_z((float)zB[0]);
    float sB1 = accB[mt][1] * sreluD_from_z((float)zB[1]);
    float sB2 = accB[mt][2] * sreluD_from_z((float)zB[2]);
    float sB3 = accB[mt][3] * sreluD_from_z((float)zB[3]);
    v4h gA, gB;
    *(v2h*)&gA       = cvt_pk(sA0, sA1);
    *((v2h*)&gA + 1) = cvt_pk(sA2, sA3);
    *(v2h*)&gB       = cvt_pk(sB0, sB1);
    *((v2h*)&gB + 1) = cvt_pk(sB2, sB3);
    *(v4h*)pA = gA;
    *(v4h*)pB = gB;
  }
}

__device__ __forceinline__ void vbwd2_l1(_Float16* zioA, _Float16* zioB,
    const _Float16* __restrict__ WT,   // V2ZT
    const _Float16* __restrict__ Wl1T, // VL1T [2][64]
    float dA0, float dA1, float dB0, float dB1, int lm, int q)
{
  v4f accA[4], accB[4];
#pragma unroll
  for (int mt = 0; mt < 4; ++mt){
    accA[mt] = (v4f){0.f,0.f,0.f,0.f};
    accB[mt] = (v4f){0.f,0.f,0.f,0.f};
  }
  const int rs = lm & 7;
#pragma unroll
  for (int kt = 0; kt < 2; ++kt){
    const int sw = (((kt*4 + q) ^ rs) << 3);
    v8h BA = *(const v8h*)(zioA + lm*64 + sw);
    v8h BB = *(const v8h*)(zioB + lm*64 + sw);
#pragma unroll
    for (int mt = 0; mt < 4; ++mt){
      v8h A = *(const v8h*)(WT + (mt*16 + lm)*64 + kt*32 + q*8);
      accA[mt] = __builtin_amdgcn_mfma_f32_16x16x32_f16(A, BA, accA[mt], 0,0,0);
      accB[mt] = __builtin_amdgcn_mfma_f32_16x16x32_f16(A, BB, accB[mt], 0,0,0);
    }
  }
#pragma unroll
  for (int mt = 0; mt < 4; ++mt){
    const int k0 = mt*16 + q*4;
    const int off = (((k0 >> 3) ^ rs) << 3) + (k0 & 7);
    v4h w0 = *(const v4h*)(Wl1T + k0);
    v4h w1 = *(const v4h*)(Wl1T + 64 + k0);
    float sA[4], sB[4];
#pragma unroll
    for (int reg = 0; reg < 4; ++reg){
      const float a1A = fmaf(dA0, (float)w0[reg], dA1 * (float)w1[reg]);
      const float a1B = fmaf(dB0, (float)w0[reg], dB1 * (float)w1[reg]);
      sA[reg] = accA[mt][reg] * sreluD(a1A);
      sB[reg] = accB[mt][reg] * sreluD(a1B);
    }
    v4h gA, gB;
    *(v2h*)&gA       = cvt_pk(sA[0], sA[1]);
    *((v2h*)&gA + 1) = cvt_pk(sA[2], sA[3]);
    *(v2h*)&gB       = cvt_pk(sB[0], sB[1]);
    *((v2h*)&gB + 1) = cvt_pk(sB[2], sB[3]);
    *(v4h*)(zioA + lm*64 + off) = gA;
    *(v4h*)(zioB + lm*64 + off) = gB;
  }
}

__device__ __forceinline__ void gacc2(v4f& aGA, v4f& aGB,
    const _Float16* __restrict__ WxTbase,
    const _Float16* ZA, const _Float16* ZB, int lm, int q)
{
  const int rs = lm & 7;
#pragma unroll
  for (int kt = 0; kt < 2; ++kt){
    const int sw = (((kt*4 + q) ^ rs) << 3);
    v8h A  = *(const v8h*)(WxTbase + lm*64 + kt*32 + q*8);
    v8h BA = *(const v8h*)(ZA + lm*64 + sw);
    v8h BB = *(const v8h*)(ZB + lm*64 + sw);
    aGA = __builtin_amdgcn_mfma_f32_16x16x32_f16(A, BA, aGA, 0,0,0);
    aGB = __builtin_amdgcn_mfma_f32_16x16x32_f16(A, BB, aGB, 0,0,0);
  }
}

__device__ __forceinline__ void vnet_body2(int b, char* smem,
  const float* __restrict__ X, const float* __restrict__ Xst,
  const float* __restrict__ Vfx)
{
  const int t  = threadIdx.x;
  const int w  = t >> 6;
  const int l  = t & 63;
  const int lm = l & 15;
  const int q  = l >> 4;
  const int rs = lm & 7;

  _Float16* const ZA2 = (_Float16*)(smem + w*8192);   // 4 x 2 KB per wave
  _Float16* const ZA3 = ZA2 + 1024;
  _Float16* const ZB2 = ZA2 + 2048;
  _Float16* const ZB3 = ZA2 + 3072;

  const int rowA = b*128 + w*32 + lm;
  const int rowB = rowA + 16;
  const int rcA = rowA < NPTS ? rowA : NPTS-1;
  const int rcB = rowB < NPTS ? rowB : NPTS-1;
  const float2 xA = *(const float2*)(X   + rcA*2);
  const float2 sA = *(const float2*)(Xst + rcA*2);
  const float2 xB = *(const float2*)(X   + rcB*2);
  const float2 sB = *(const float2*)(Xst + rcB*2);
  const float dA0 = xA.x - sA.x, dA1 = xA.y - sA.y;
  const float dB0 = xB.x - sB.x, dB1 = xB.y - sB.y;
  const float vfx0 = Vfx[0], vfx1 = Vfx[1];

  // fwd: z2 (z1 in registers), z3
  vfwd2_l2(ZA2, ZB2, g_w16 + OFF_V2Z, g_w16 + OFF_V2XT, g_w16 + OFF_VL1T,
           dA0, dA1, dB0, dB1, lm, q);
  vfwd2(ZA2, ZA3, ZB2, ZB3, g_w16 + OFF_V3Z, g_w16 + OFF_V3XT,
        dA0, dA1, dB0, dB1, lm, q);

  // zf head for both (A row 0 = Vfz)
  float VVrA, sfA, VVrB, sfB;
  {
    v4f aSA = (v4f){0.f,0.f,0.f,0.f};
    v4f aSB = (v4f){0.f,0.f,0.f,0.f};
#pragma unroll
    for (int kt = 0; kt < 2; ++kt){
      const int sw = (((kt*4 + q) ^ rs) << 3);
      v8h A  = *(const v8h*)(g_w16 + OFF_VFZ + lm*64 + kt*32 + q*8);
      v8h BA = *(const v8h*)(ZA3 + lm*64 + sw);
      v8h BB = *(const v8h*)(ZB3 + lm*64 + sw);
      aSA = __builtin_amdgcn_mfma_f32_16x16x32_f16(A, BA, aSA, 0,0,0);
      aSB = __builtin_amdgcn_mfma_f32_16x16x32_f16(A, BB, aSB, 0,0,0);
    }
    const float afA = fmaf(vfx0, dA0, fmaf(vfx1, dA1, aSA[0]));
    const float zfA = srelu(afA);
    VVrA = srelu(zfA) + 0.01f * fmaf(dA0, dA0, dA1*dA1);
    sfA  = sreluD(zfA) * sreluD(afA);
    const float afB = fmaf(vfx0, dB0, fmaf(vfx1, dB1, aSB[0]));
    const float zfB = srelu(afB);
    VVrB = srelu(zfB) + 0.01f * fmaf(dB0, dB0, dB1*dB1);
    sfB  = sreluD(zfB) * sreluD(afB);
  }

  // u3 = Vfz * srelu'(a3) (sf deferred; in place over Z3)
#pragma unroll
  for (int cc = 0; cc < 2; ++cc){
    const int c = q*2 + cc;
    const int sw = ((c ^ rs) << 3);
    v8h vf = *(const v8h*)(g_w16 + OFF_VFZ + c*8);
    _Float16* pA = ZA3 + lm*64 + sw;
    _Float16* pB = ZB3 + lm*64 + sw;
    v8h zA = *(const v8h*)pA;
    v8h zB = *(const v8h*)pB;
    v8h uA, uB;
#pragma unroll
    for (int j2 = 0; j2 < 4; ++j2){
      float a0 = (float)vf[2*j2  ] * sreluD_from_z((float)zA[2*j2  ]);
      float a1 = (float)vf[2*j2+1] * sreluD_from_z((float)zA[2*j2+1]);
      float b0 = (float)vf[2*j2  ] * sreluD_from_z((float)zB[2*j2  ]);
      float b1 = (float)vf[2*j2+1] * sreluD_from_z((float)zB[2*j2+1]);
      ((v2h*)&uA)[j2] = cvt_pk(a0, a1);
      ((v2h*)&uB)[j2] = cvt_pk(b0, b1);
    }
    *(v8h*)pA = uA;
    *(v8h*)pB = uB;
  }

  // incremental gradV, interleaved with backward (arena reuse)
  v4f aGA = (v4f){0.f,0.f,0.f,0.f};
  v4f aGB = (v4f){0.f,0.f,0.f,0.f};

  gacc2(aGA, aGB, g_w16 + OFF_V3XT, ZA3, ZB3, lm, q);             // L3 (ga3=u3)
  vbwd2(ZA3, ZA2, ZB3, ZB2, g_w16 + OFF_V3ZT, lm, q);             // ga2 -> Z2
  gacc2(aGA, aGB, g_w16 + OFF_V2XT, ZA2, ZB2, lm, q);             // L2
  vbwd2_l1(ZA2, ZB2, g_w16 + OFF_V2ZT, g_w16 + OFF_VL1T,
           dA0, dA1, dB0, dB1, lm, q);                            // ga1 -> Z2
  gacc2(aGA, aGB, g_w16 + OFF_VL1T, ZA2, ZB2, lm, q);             // L1

  const float g0A = fmaf(0.02f, dA0, sfA * (vfx0 + aGA[0]));
  const float g1A = fmaf(0.02f, dA1, sfA * (vfx1 + aGA[1]));
  const float g0B = fmaf(0.02f, dB0, sfB * (vfx0 + aGB[0]));
  const float g1B = fmaf(0.02f, dB1, sfB * (vfx1 + aGB[1]));

  if (q == 0){
    if (rowA < NPTS) g_grad[rowA] = make_float4(g0A, g1A, VVrA, 0.f);
    if (rowB < NPTS) g_grad[rowB] = make_float4(g0B, g1B, VVrB, 0.f);
  }
}

// ================= fused heterogeneous kernel (NO barriers) =================
__global__ __launch_bounds__(256, 4) void fused_kernel(
  const float* __restrict__ X, const float* __restrict__ Xst,
  const float* __restrict__ Vfx,
  const float* __restrict__ f1b, const float* __restrict__ f2b,
  const float* __restrict__ f3b, const float* __restrict__ f4b,
  const float* __restrict__ f5b, const float* __restrict__ ffb)
{
  __shared__ __align__(16) char smem[32768];   // fhat 4x8KB | vnet 4x8KB
  const int g = blockIdx.x;
  if ((g & 1) == 0){
    fhat_body(g >> 1, smem, X, f1b, f2b, f3b, f4b, f5b, ffb);
  } else {
    vnet_body2(g >> 1, smem, X, Xst, Vfx);
  }
}

// ================= combine epilogue (2 rows/thread, ~16 MB) =================
__global__ __launch_bounds__(256) void combine_kernel(float* __restrict__ out)
{
  const int idx = blockIdx.x * 256 + threadIdx.x;
  const int i0 = idx * 2;
  if (i0 >= NPTS) return;
  const float4 fh2 = *(const float4*)(g_fh + i0*2);
  const float4 ga = g_grad[i0];
  const float4 gb = g_grad[i0 + 1];
  float4 o;
  {
    const float Vn  = fmaf(ga.x, ga.x, ga.y*ga.y);
    const float num = fmaf(0.1f, ga.z, fmaf(fh2.x, ga.x, fh2.y*ga.y));
    const float fm  = fmaxf(num, 0.f) / (Vn + 1e-10f);
    o.x = fmaf(-ga.x, fm, fh2.x);
    o.y = fmaf(-ga.y, fm, fh2.y);
  }
  {
    const float Vn  = fmaf(gb.x, gb.x, gb.y*gb.y);
    const float num = fmaf(0.1f, gb.z, fmaf(fh2.z, gb.x, fh2.w*gb.y));
    const float fm  = fmaxf(num, 0.f) / (Vn + 1e-10f);
    o.z = fmaf(-gb.x, fm, fh2.z);
    o.w = fmaf(-gb.y, fm, fh2.w);
  }
  *(float4*)(out + i0*2) = o;
}

extern "C" void kernel_launch(void* const* d_in, const int* in_sizes, int n_in,
                              void* d_out, int out_size, void* d_ws, size_t ws_size,
                              hipStream_t stream)
{
  (void)d_ws; (void)ws_size; (void)n_in; (void)in_sizes; (void)out_size;
  const float* X   = (const float*)d_in[0];
  const float* Xst = (const float*)d_in[1];
  const float* Vl1 = (const float*)d_in[2];
  const float* V2x = (const float*)d_in[3];
  const float* V2z = (const float*)d_in[4];
  const float* V3x = (const float*)d_in[5];
  const float* V3z = (const float*)d_in[6];
  const float* Vfx = (const float*)d_in[7];
  const float* Vfz = (const float*)d_in[8];
  const float* f1w = (const float*)d_in[9];
  const float* f1b = (const float*)d_in[10];
  const float* f2w = (const float*)d_in[11];
  const float* f2b = (const float*)d_in[12];
  const float* f3w = (const float*)d_in[13];
  const float* f3b = (const float*)d_in[14];
  const float* f4w = (const float*)d_in[15];
  const float* f4b = (const float*)d_in[16];
  const float* f5w = (const float*)d_in[17];
  const float* f5b = (const float*)d_in[18];
  const float* ffw = (const float*)d_in[19];
  const float* ffb = (const float*)d_in[20];

  prep_kernel<<<(W16_TOTAL + 255)/256, 256, 0, stream>>>(
      f2w, f3w, f4w, f5w, V2z, V3z, Vl1, V2x, V3x, Vfz, ffw, f1w);
  fused_kernel<<<FUSED_GRID, 256, 0, stream>>>(
      X, Xst, Vfx, f1b, f2b, f3b, f4b, f5b, ffb);
  combine_kernel<<<(NPTS/2 + 255)/256, 256, 0, stream>>>((float*)d_out);
}

// Round 3
// 272.582 us; speedup vs baseline: 2.2874x; 2.2874x over previous
//
#include <hip/hip_runtime.h>

// ICNN_net_1503238553972 — round 21: R18 structure restored (best, 237us
// fused) + targeted VALU cuts. R19 (more occupancy) and R20 (barrier-free,
// per-wave weights) both regressed — R18's 4-wave shared-H lockstep is the
// validated structure. Changes vs R18:
//  (1) f1 via MFMA over zero-padded K=32 weights (removes 64 v_dot2 + 64
//      scalar global loads per thread), streamed 2 accs at a time.
//  (2) ff tail via MFMA on wave-local rows (removes 64 v_dot2 + 16
//      ds_read_b128 per thread).
//  (3) bias folded into MFMA C-init (removes 64 v_add per wave-layer).
//  (4) barriers = s_waitcnt lgkmcnt(0) + s_barrier (no vmcnt drain;
//      only LDS ordering is needed).
// vnet body identical to R18 ILP-2. LDS 32KB, launch_bounds(256,4).

typedef _Float16 v2h __attribute__((ext_vector_type(2)));
typedef __fp16   v2hf __attribute__((ext_vector_type(2)));
typedef _Float16 v4h __attribute__((ext_vector_type(4)));
typedef _Float16 v8h __attribute__((ext_vector_type(8)));
typedef float    v4f __attribute__((ext_vector_type(4)));

__device__ __forceinline__ v2h cvt_pk(float a, float b){
  v2hf r = __builtin_amdgcn_cvt_pkrtz(a, b);
  union { v2hf f; v2h h; } u; u.f = r;
  return u.h;
}

#define NPTS 500000
#define FH_BLK  ((NPTS + 127) / 128)   // 3907
#define FUSED_GRID (FH_BLK * 2)        // 7814 (even=fhat, odd=vnet)

// LDS-only barrier: LDS ordering without draining vmcnt (weights in flight)
#define BAR_LDS() asm volatile("s_waitcnt lgkmcnt(0)\n\ts_barrier" ::: "memory")

// offsets in halves inside g_w16
#define OFF_FW    0               // f2..f5: L*16384, [o*128+k]
#define OFF_V2Z   65536           // [j*64+k]
#define OFF_V3Z   69632
#define OFF_V2ZT  73728           // [k*64+j]
#define OFF_V3ZT  77824
#define OFF_VL1T  81920           // [c*64+j]
#define OFF_V2XT  82048
#define OFF_V3XT  82176
#define OFF_VFZ   82304           // [64]
#define OFF_FFW   82368           // [c*128+k]
#define OFF_F1W   82624           // [oc*2+c]
#define OFF_F1P   82880           // f1 padded [o*32+k], k<2 valid else 0
#define W16_DATA  86976
#define W16_TOTAL (W16_DATA + 2048)   // zero pad: junk A-rows stay in-bounds

__device__ __align__(16) _Float16 g_w16[W16_TOTAL];
__device__ __align__(16) float    g_fh[NPTS * 2];   // f_hat per row (fp32)
__device__ __align__(16) float4   g_grad[NPTS];     // (g0, g1, V, pad)

#if defined(__has_builtin)
#if __has_builtin(__builtin_amdgcn_fdot2)
#define FDOT2(a,b,c) __builtin_amdgcn_fdot2((a),(b),(c),false)
#endif
#endif
#ifndef FDOT2
__device__ __forceinline__ float fdot2_fb(v2h a, v2h b, float c){
  return fmaf((float)a.x, (float)b.x, fmaf((float)a.y, (float)b.y, c));
}
#define FDOT2(a,b,c) fdot2_fb((a),(b),(c))
#endif

__device__ __forceinline__ float srelu(float x){
  float c = fminf(fmaxf(x, 0.f), 1.f);
  return c * fmaf(-0.5f, c, x);
}
__device__ __forceinline__ float sreluD(float x){
  return fminf(fmaxf(x, 0.f), 1.f);
}
__device__ __forceinline__ float sreluD_from_z(float z){
  return fminf(sqrtf(2.f * z), 1.f);
}

// ---- packed f16 activations (2 f32 in -> 2 f16 out) ----
__device__ __forceinline__ v2h lrelu_pk(float a, float b){
  v2h x = cvt_pk(a, b);
  v2h m = x * (v2h){(_Float16)0.01f, (_Float16)0.01f};
  return __builtin_elementwise_max(x, m);
}
__device__ __forceinline__ v2h srelu_pk(float a, float b){
  v2h x = cvt_pk(a, b);
  const v2h z0 = (v2h){(_Float16)0.f, (_Float16)0.f};
  const v2h o1 = (v2h){(_Float16)1.f, (_Float16)1.f};
  const v2h hf = (v2h){(_Float16)0.5f, (_Float16)0.5f};
  v2h c = __builtin_elementwise_min(__builtin_elementwise_max(x, z0), o1);
  v2h t = x - c * hf;
  return c * t;
}

// ---------------- prep: fp32 weights -> f16 layouts (+zero pad) ----------------
__global__ __launch_bounds__(256) void prep_kernel(
  const float* __restrict__ f2w, const float* __restrict__ f3w,
  const float* __restrict__ f4w, const float* __restrict__ f5w,
  const float* __restrict__ V2z, const float* __restrict__ V3z,
  const float* __restrict__ Vl1, const float* __restrict__ V2x,
  const float* __restrict__ V3x, const float* __restrict__ Vfz,
  const float* __restrict__ ffw, const float* __restrict__ f1w)
{
  const int i = blockIdx.x * 256 + threadIdx.x;
  if (i >= W16_TOTAL) return;
  if (i >= W16_DATA){ g_w16[i] = (_Float16)0.f; return; }
  float v;
  if (i < 65536){
    const float* W[4] = {f2w, f3w, f4w, f5w};
    v = W[i >> 14][i & 16383];
  } else if (i < 69632)  v = V2z[i - 65536];
  else if (i < 73728)    v = V3z[i - 69632];
  else if (i < 77824){ int r = i - 73728; v = V2z[(r & 63)*64 + (r >> 6)]; }
  else if (i < 81920){ int r = i - 77824; v = V3z[(r & 63)*64 + (r >> 6)]; }
  else if (i < 82048){ int r = i - 81920; v = Vl1[(r & 63)*2 + (r >> 6)]; }
  else if (i < 82176){ int r = i - 82048; v = V2x[(r & 63)*2 + (r >> 6)]; }
  else if (i < 82304){ int r = i - 82176; v = V3x[(r & 63)*2 + (r >> 6)]; }
  else if (i < 82368)    v = Vfz[i - 82304];
  else if (i < 82624)    v = ffw[i - 82368];
  else if (i < 82880)    v = f1w[i - 82624];
  else { int r = i - 82880; int k = r & 31; v = (k < 2) ? f1w[(r >> 5)*2 + k] : 0.f; }
  g_w16[i] = (_Float16)v;
}

// ================= fhat block body: 256 thr, 128 rows (R18 structure) =================
__device__ __forceinline__ void fh_layer(_Float16* H,
    const _Float16* __restrict__ Wl, const float* __restrict__ Bp,
    int w, int lm, int q)
{
  // bias as MFMA C-init: acc reg r holds output feature o0+r, uniform over
  // lanes' col and nt — exact same math as post-add.
  const v4f bva = *(const v4f*)(Bp + w*32 + q*4);
  const v4f bvb = *(const v4f*)(Bp + w*32 + 16 + q*4);
  v4f acc[2][8];
#pragma unroll
  for (int nt = 0; nt < 8; ++nt){
    acc[0][nt] = bva;
    acc[1][nt] = bvb;
  }

#pragma unroll
  for (int kt = 0; kt < 4; ++kt){
    const int sw = ((kt*4 + q) ^ lm) << 3;
    v8h A0 = *(const v8h*)(Wl + (w*32      + lm)*128 + kt*32 + q*8);
    v8h A1 = *(const v8h*)(Wl + (w*32 + 16 + lm)*128 + kt*32 + q*8);
#pragma unroll
    for (int nt = 0; nt < 8; ++nt){
      v8h B = *(const v8h*)(H + (nt*16 + lm)*128 + sw);
      acc[0][nt] = __builtin_amdgcn_mfma_f32_16x16x32_f16(A0, B, acc[0][nt], 0,0,0);
      acc[1][nt] = __builtin_amdgcn_mfma_f32_16x16x32_f16(A1, B, acc[1][nt], 0,0,0);
    }
  }
  BAR_LDS();
#pragma unroll
  for (int mt = 0; mt < 2; ++mt){
    const int o0 = w*32 + mt*16 + q*4;
    const int coff = (((o0 >> 3) ^ lm) << 3) + (o0 & 7);
#pragma unroll
    for (int nt = 0; nt < 8; ++nt){
      v4h hv;
      *(v2h*)&hv       = lrelu_pk(acc[mt][nt][0], acc[mt][nt][1]);
      *((v2h*)&hv + 1) = lrelu_pk(acc[mt][nt][2], acc[mt][nt][3]);
      *(v4h*)(H + (nt*16 + lm)*128 + coff) = hv;
    }
  }
  BAR_LDS();
}

__device__ __forceinline__ void fhat_body(int b, _Float16* H,
  const float* __restrict__ X,
  const float* __restrict__ f1b, const float* __restrict__ f2b,
  const float* __restrict__ f3b, const float* __restrict__ f4b,
  const float* __restrict__ f5b, const float* __restrict__ ffb)
{
  const int t  = threadIdx.x;
  const int w  = t >> 6;
  const int l  = t & 63;
  const int lm = l & 15;
  const int q  = l >> 4;
  const int row0 = b*128 + w*32;   // wave's 32 rows (f1 / ff stages)

  // ---- f1 via MFMA: A = f1w padded to K=32, B = x (q==0 lanes k=0,1) ----
  // Streamed with only 2 live accumulators (avoid R20's register blowup).
  {
    int r0 = row0 + lm;      if (r0 > NPTS-1) r0 = NPTS-1;
    int r1 = row0 + 16 + lm; if (r1 > NPTS-1) r1 = NPTS-1;
    const float2 x0 = *(const float2*)(X + r0*2);
    const float2 x1 = *(const float2*)(X + r1*2);
    v8h Bx0 = (v8h){(_Float16)0.f,(_Float16)0.f,(_Float16)0.f,(_Float16)0.f,
                    (_Float16)0.f,(_Float16)0.f,(_Float16)0.f,(_Float16)0.f};
    v8h Bx1 = Bx0;
    if (q == 0){
      Bx0[0] = (_Float16)x0.x; Bx0[1] = (_Float16)x0.y;
      Bx1[0] = (_Float16)x1.x; Bx1[1] = (_Float16)x1.y;
    }
#pragma unroll
    for (int mt = 0; mt < 8; ++mt){
      const int o0 = mt*16 + q*4;
      const v4f bv = *(const v4f*)(f1b + o0);
      v8h A = *(const v8h*)(g_w16 + OFF_F1P + (mt*16 + lm)*32 + q*8);
      v4f a0 = __builtin_amdgcn_mfma_f32_16x16x32_f16(A, Bx0, bv, 0,0,0);
      v4f a1 = __builtin_amdgcn_mfma_f32_16x16x32_f16(A, Bx1, bv, 0,0,0);
      const int coff = (((o0 >> 3) ^ lm) << 3) + (o0 & 7);
      v4h h0, h1;
      *(v2h*)&h0       = lrelu_pk(a0[0], a0[1]);
      *((v2h*)&h0 + 1) = lrelu_pk(a0[2], a0[3]);
      *(v2h*)&h1       = lrelu_pk(a1[0], a1[1]);
      *((v2h*)&h1 + 1) = lrelu_pk(a1[2], a1[3]);
      *(v4h*)(H + (w*32 + lm)*128 + coff)      = h0;
      *(v4h*)(H + (w*32 + 16 + lm)*128 + coff) = h1;
    }
  }
  BAR_LDS();

  fh_layer(H, g_w16 + OFF_FW,         f2b, w, lm, q);
  fh_layer(H, g_w16 + OFF_FW + 16384, f3b, w, lm, q);
  fh_layer(H, g_w16 + OFF_FW + 32768, f4b, w, lm, q);
  fh_layer(H, g_w16 + OFF_FW + 49152, f5b, w, lm, q);

  // ---- ff via MFMA on wave-local rows: A rows 0,1 = ffw (junk rows
  //      in-bounds, ignored); output feats 0,1 land in q==0 regs 0,1 ----
  {
    v4f a0 = (v4f){0.f,0.f,0.f,0.f};
    v4f a1 = (v4f){0.f,0.f,0.f,0.f};
#pragma unroll
    for (int kt = 0; kt < 4; ++kt){
      const int sw = ((kt*4 + q) ^ lm) << 3;
      v8h A  = *(const v8h*)(g_w16 + OFF_FFW + lm*128 + kt*32 + q*8);
      v8h B0 = *(const v8h*)(H + (w*32 + lm)*128 + sw);
      v8h B1 = *(const v8h*)(H + (w*32 + 16 + lm)*128 + sw);
      a0 = __builtin_amdgcn_mfma_f32_16x16x32_f16(A, B0, a0, 0,0,0);
      a1 = __builtin_amdgcn_mfma_f32_16x16x32_f16(A, B1, a1, 0,0,0);
    }
    if (q == 0){
      const float fb0 = ffb[0], fb1 = ffb[1];
      const int r0 = row0 + lm, r1 = row0 + 16 + lm;
      if (r0 < NPTS) *(float2*)(g_fh + r0*2) = make_float2(a0[0] + fb0, a0[1] + fb1);
      if (r1 < NPTS) *(float2*)(g_fh + r1*2) = make_float2(a1[0] + fb0, a1[1] + fb1);
    }
  }
}

// ================= vnet: R18 ILP-2, 2 arenas/pipeline (barrier-free) =================
__device__ __forceinline__ void vfwd2_l2(_Float16* zoutA, _Float16* zoutB,
    const _Float16* __restrict__ Wz,   // V2Z [o][k]
    const _Float16* __restrict__ WxT,  // V2XT [2][64]
    const _Float16* __restrict__ Wl1T, // VL1T [2][64]
    float dA0, float dA1, float dB0, float dB1, int lm, int q)
{
  v4f accA[4], accB[4];
#pragma unroll
  for (int mt = 0; mt < 4; ++mt){
    accA[mt] = (v4f){0.f,0.f,0.f,0.f};
    accB[mt] = (v4f){0.f,0.f,0.f,0.f};
  }
  const int rs = lm & 7;
#pragma unroll
  for (int kt = 0; kt < 2; ++kt){
    v8h w0 = *(const v8h*)(Wl1T + kt*32 + q*8);
    v8h w1 = *(const v8h*)(Wl1T + 64 + kt*32 + q*8);
    v8h BA, BB;
#pragma unroll
    for (int j2 = 0; j2 < 4; ++j2){
      const float a0 = (float)w0[2*j2  ], a1 = (float)w0[2*j2+1];
      const float c0 = (float)w1[2*j2  ], c1 = (float)w1[2*j2+1];
      ((v2h*)&BA)[j2] = srelu_pk(fmaf(dA0,a0,dA1*c0), fmaf(dA0,a1,dA1*c1));
      ((v2h*)&BB)[j2] = srelu_pk(fmaf(dB0,a0,dB1*c0), fmaf(dB0,a1,dB1*c1));
    }
#pragma unroll
    for (int mt = 0; mt < 4; ++mt){
      v8h A = *(const v8h*)(Wz + (mt*16 + lm)*64 + kt*32 + q*8);
      accA[mt] = __builtin_amdgcn_mfma_f32_16x16x32_f16(A, BA, accA[mt], 0,0,0);
      accB[mt] = __builtin_amdgcn_mfma_f32_16x16x32_f16(A, BB, accB[mt], 0,0,0);
    }
  }
#pragma unroll
  for (int mt = 0; mt < 4; ++mt){
    const int o0 = mt*16 + q*4;
    const int off = (((o0 >> 3) ^ rs) << 3) + (o0 & 7);
    float vA[4], vB[4];
#pragma unroll
    for (int reg = 0; reg < 4; ++reg){
      const float wx0 = (float)WxT[o0 + reg];
      const float wx1 = (float)WxT[64 + o0 + reg];
      vA[reg] = accA[mt][reg] + wx0*dA0 + wx1*dA1;
      vB[reg] = accB[mt][reg] + wx0*dB0 + wx1*dB1;
    }
    v4h hA, hB;
    *(v2h*)&hA       = srelu_pk(vA[0], vA[1]);
    *((v2h*)&hA + 1) = srelu_pk(vA[2], vA[3]);
    *(v2h*)&hB       = srelu_pk(vB[0], vB[1]);
    *((v2h*)&hB + 1) = srelu_pk(vB[2], vB[3]);
    *(v4h*)(zoutA + lm*64 + off) = hA;
    *(v4h*)(zoutB + lm*64 + off) = hB;
  }
}

__device__ __forceinline__ void vfwd2(const _Float16* zinA, _Float16* zoutA,
    const _Float16* zinB, _Float16* zoutB,
    const _Float16* __restrict__ Wz, const _Float16* __restrict__ WxT,
    float dA0, float dA1, float dB0, float dB1, int lm, int q)
{
  v4f accA[4], accB[4];
#pragma unroll
  for (int mt = 0; mt < 4; ++mt){
    accA[mt] = (v4f){0.f,0.f,0.f,0.f};
    accB[mt] = (v4f){0.f,0.f,0.f,0.f};
  }
  const int rs = lm & 7;
#pragma unroll
  for (int kt = 0; kt < 2; ++kt){
    const int sw = (((kt*4 + q) ^ rs) << 3);
    v8h BA = *(const v8h*)(zinA + lm*64 + sw);
    v8h BB = *(const v8h*)(zinB + lm*64 + sw);
#pragma unroll
    for (int mt = 0; mt < 4; ++mt){
      v8h A = *(const v8h*)(Wz + (mt*16 + lm)*64 + kt*32 + q*8);
      accA[mt] = __builtin_amdgcn_mfma_f32_16x16x32_f16(A, BA, accA[mt], 0,0,0);
      accB[mt] = __builtin_amdgcn_mfma_f32_16x16x32_f16(A, BB, accB[mt], 0,0,0);
    }
  }
#pragma unroll
  for (int mt = 0; mt < 4; ++mt){
    const int o0 = mt*16 + q*4;
    const int off = (((o0 >> 3) ^ rs) << 3) + (o0 & 7);
    float vA[4], vB[4];
#pragma unroll
    for (int reg = 0; reg < 4; ++reg){
      const float wx0 = (float)WxT[o0 + reg];
      const float wx1 = (float)WxT[64 + o0 + reg];
      vA[reg] = accA[mt][reg] + wx0*dA0 + wx1*dA1;
      vB[reg] = accB[mt][reg] + wx0*dB0 + wx1*dB1;
    }
    v4h hA, hB;
    *(v2h*)&hA       = srelu_pk(vA[0], vA[1]);
    *((v2h*)&hA + 1) = srelu_pk(vA[2], vA[3]);
    *(v2h*)&hB       = srelu_pk(vB[0], vB[1]);
    *((v2h*)&hB + 1) = srelu_pk(vB[2], vB[3]);
    *(v4h*)(zoutA + lm*64 + off) = hA;
    *(v4h*)(zoutB + lm*64 + off) = hB;
  }
}

__device__ __forceinline__ void vbwd2(const _Float16* ginA, _Float16* zioA,
    const _Float16* ginB, _Float16* zioB,
    const _Float16* __restrict__ WT, int lm, int q)
{
  v4f accA[4], accB[4];
#pragma unroll
  for (int mt = 0; mt < 4; ++mt){
    accA[mt] = (v4f){0.f,0.f,0.f,0.f};
    accB[mt] = (v4f){0.f,0.f,0.f,0.f};
  }
  const int rs = lm & 7;
#pragma unroll
  for (int kt = 0; kt < 2; ++kt){
    const int sw = (((kt*4 + q) ^ rs) << 3);
    v8h BA = *(const v8h*)(ginA + lm*64 + sw);
    v8h BB = *(const v8h*)(ginB + lm*64 + sw);
#pragma unroll
    for (int mt = 0; mt < 4; ++mt){
      v8h A = *(const v8h*)(WT + (mt*16 + lm)*64 + kt*32 + q*8);
      accA[mt] = __builtin_amdgcn_mfma_f32_16x16x32_f16(A, BA, accA[mt], 0,0,0);
      accB[mt] = __builtin_amdgcn_mfma_f32_16x16x32_f16(A, BB, accB[mt], 0,0,0);
    }
  }
#pragma unroll
  for (int mt = 0; mt < 4; ++mt){
    const int k0 = mt*16 + q*4;
    const int off = (((k0 >> 3) ^ rs) << 3) + (k0 & 7);
    _Float16* pA = zioA + lm*64 + off;
    _Float16* pB = zioB + lm*64 + off;
    v4h zA = *(const v4h*)pA;
    v4h zB = *(const v4h*)pB;
    float sA0 = accA[mt][0] * sreluD_from_z((float)zA[0]);
    float sA1 = accA[mt][1] * sreluD_from_z((float)zA[1]);
    float sA2 = accA[mt][2] * sreluD_from_z((float)zA[2]);
    float sA3 = accA[mt][3] * sreluD_from_z((float)zA[3]);
    float sB0 = accB[mt][0] * sreluD_from_z((float)zB[0]);
    float sB1 = accB[mt][1] * sreluD_from_z((float)zB[1]);
    float sB2 = accB[mt][2] * sreluD_from_z((float)zB[2]);
    float sB3 = accB[mt][3] * sreluD_from_z((float)zB[3]);
    v4h gA, gB;
    *(v2h*)&gA       = cvt_pk(sA0, sA1);
    *((v2h*)&gA + 1) = cvt_pk(sA2, sA3);
    *(v2h*)&gB       = cvt_pk(sB0, sB1);
    *((v2h*)&gB + 1) = cvt_pk(sB2, sB3);
    *(v4h*)pA = gA;
    *(v4h*)pB = gB;
  }
}

__device__ __forceinline__ void vbwd2_l1(_Float16* zioA, _Float16* zioB,
    const _Float16* __restrict__ WT,   // V2ZT
    const _Float16* __restrict__ Wl1T, // VL1T [2][64]
    float dA0, float dA1, float dB0, float dB1, int lm, int q)
{
  v4f accA[4], accB[4];
#pragma unroll
  for (int mt = 0; mt < 4; ++mt){
    accA[mt] = (v4f){0.f,0.f,0.f,0.f};
    accB[mt] = (v4f){0.f,0.f,0.f,0.f};
  }
  const int rs = lm & 7;
#pragma unroll
  for (int kt = 0; kt < 2; ++kt){
    const int sw = (((kt*4 + q) ^ rs) << 3);
    v8h BA = *(const v8h*)(zioA + lm*64 + sw);
    v8h BB = *(const v8h*)(zioB + lm*64 + sw);
#pragma unroll
    for (int mt = 0; mt < 4; ++mt){
      v8h A = *(const v8h*)(WT + (mt*16 + lm)*64 + kt*32 + q*8);
      accA[mt] = __builtin_amdgcn_mfma_f32_16x16x32_f16(A, BA, accA[mt], 0,0,0);
      accB[mt] = __builtin_amdgcn_mfma_f32_16x16x32_f16(A, BB, accB[mt], 0,0,0);
    }
  }
#pragma unroll
  for (int mt = 0; mt < 4; ++mt){
    const int k0 = mt*16 + q*4;
    const int off = (((k0 >> 3) ^ rs) << 3) + (k0 & 7);
    v4h w0 = *(const v4h*)(Wl1T + k0);
    v4h w1 = *(const v4h*)(Wl1T + 64 + k0);
    float sA[4], sB[4];
#pragma unroll
    for (int reg = 0; reg < 4; ++reg){
      const float a1A = fmaf(dA0, (float)w0[reg], dA1 * (float)w1[reg]);
      const float a1B = fmaf(dB0, (float)w0[reg], dB1 * (float)w1[reg]);
      sA[reg] = accA[mt][reg] * sreluD(a1A);
      sB[reg] = accB[mt][reg] * sreluD(a1B);
    }
    v4h gA, gB;
    *(v2h*)&gA       = cvt_pk(sA[0], sA[1]);
    *((v2h*)&gA + 1) = cvt_pk(sA[2], sA[3]);
    *(v2h*)&gB       = cvt_pk(sB[0], sB[1]);
    *((v2h*)&gB + 1) = cvt_pk(sB[2], sB[3]);
    *(v4h*)(zioA + lm*64 + off) = gA;
    *(v4h*)(zioB + lm*64 + off) = gB;
  }
}

__device__ __forceinline__ void gacc2(v4f& aGA, v4f& aGB,
    const _Float16* __restrict__ WxTbase,
    const _Float16* ZA, const _Float16* ZB, int lm, int q)
{
  const int rs = lm & 7;
#pragma unroll
  for (int kt = 0; kt < 2; ++kt){
    const int sw = (((kt*4 + q) ^ rs) << 3);
    v8h A  = *(const v8h*)(WxTbase + lm*64 + kt*32 + q*8);
    v8h BA = *(const v8h*)(ZA + lm*64 + sw);
    v8h BB = *(const v8h*)(ZB + lm*64 + sw);
    aGA = __builtin_amdgcn_mfma_f32_16x16x32_f16(A, BA, aGA, 0,0,0);
    aGB = __builtin_amdgcn_mfma_f32_16x16x32_f16(A, BB, aGB, 0,0,0);
  }
}

__device__ __forceinline__ void vnet_body2(int b, char* smem,
  const float* __restrict__ X, const float* __restrict__ Xst,
  const float* __restrict__ Vfx)
{
  const int t  = threadIdx.x;
  const int w  = t >> 6;
  const int l  = t & 63;
  const int lm = l & 15;
  const int q  = l >> 4;
  const int rs = lm & 7;

  _Float16* const ZA2 = (_Float16*)(smem + w*8192);   // 4 x 2 KB per wave
  _Float16* const ZA3 = ZA2 + 1024;
  _Float16* const ZB2 = ZA2 + 2048;
  _Float16* const ZB3 = ZA2 + 3072;

  const int rowA = b*128 + w*32 + lm;
  const int rowB = rowA + 16;
  const int rcA = rowA < NPTS ? rowA : NPTS-1;
  const int rcB = rowB < NPTS ? rowB : NPTS-1;
  const float2 xA = *(const float2*)(X   + rcA*2);
  const float2 sA = *(const float2*)(Xst + rcA*2);
  const float2 xB = *(const float2*)(X   + rcB*2);
  const float2 sB = *(const float2*)(Xst + rcB*2);
  const float dA0 = xA.x - sA.x, dA1 = xA.y - sA.y;
  const float dB0 = xB.x - sB.x, dB1 = xB.y - sB.y;
  const float vfx0 = Vfx[0], vfx1 = Vfx[1];

  // fwd: z2 (z1 in registers), z3
  vfwd2_l2(ZA2, ZB2, g_w16 + OFF_V2Z, g_w16 + OFF_V2XT, g_w16 + OFF_VL1T,
           dA0, dA1, dB0, dB1, lm, q);
  vfwd2(ZA2, ZA3, ZB2, ZB3, g_w16 + OFF_V3Z, g_w16 + OFF_V3XT,
        dA0, dA1, dB0, dB1, lm, q);

  // zf head for both (A row 0 = Vfz)
  float VVrA, sfA, VVrB, sfB;
  {
    v4f aSA = (v4f){0.f,0.f,0.f,0.f};
    v4f aSB = (v4f){0.f,0.f,0.f,0.f};
#pragma unroll
    for (int kt = 0; kt < 2; ++kt){
      const int sw = (((kt*4 + q) ^ rs) << 3);
      v8h A  = *(const v8h*)(g_w16 + OFF_VFZ + lm*64 + kt*32 + q*8);
      v8h BA = *(const v8h*)(ZA3 + lm*64 + sw);
      v8h BB = *(const v8h*)(ZB3 + lm*64 + sw);
      aSA = __builtin_amdgcn_mfma_f32_16x16x32_f16(A, BA, aSA, 0,0,0);
      aSB = __builtin_amdgcn_mfma_f32_16x16x32_f16(A, BB, aSB, 0,0,0);
    }
    const float afA = fmaf(vfx0, dA0, fmaf(vfx1, dA1, aSA[0]));
    const float zfA = srelu(afA);
    VVrA = srelu(zfA) + 0.01f * fmaf(dA0, dA0, dA1*dA1);
    sfA  = sreluD(zfA) * sreluD(afA);
    const float afB = fmaf(vfx0, dB0, fmaf(vfx1, dB1, aSB[0]));
    const float zfB = srelu(afB);
    VVrB = srelu(zfB) + 0.01f * fmaf(dB0, dB0, dB1*dB1);
    sfB  = sreluD(zfB) * sreluD(afB);
  }

  // u3 = Vfz * srelu'(a3) (sf deferred; in place over Z3)
#pragma unroll
  for (int cc = 0; cc < 2; ++cc){
    const int c = q*2 + cc;
    const int sw = ((c ^ rs) << 3);
    v8h vf = *(const v8h*)(g_w16 + OFF_VFZ + c*8);
    _Float16* pA = ZA3 + lm*64 + sw;
    _Float16* pB = ZB3 + lm*64 + sw;
    v8h zA = *(const v8h*)pA;
    v8h zB = *(const v8h*)pB;
    v8h uA, uB;
#pragma unroll
    for (int j2 = 0; j2 < 4; ++j2){
      float a0 = (float)vf[2*j2  ] * sreluD_from_z((float)zA[2*j2  ]);
      float a1 = (float)vf[2*j2+1] * sreluD_from_z((float)zA[2*j2+1]);
      float b0 = (float)vf[2*j2  ] * sreluD_from_z((float)zB[2*j2  ]);
      float b1 = (float)vf[2*j2+1] * sreluD_from_z((float)zB[2*j2+1]);
      ((v2h*)&uA)[j2] = cvt_pk(a0, a1);
      ((v2h*)&uB)[j2] = cvt_pk(b0, b1);
    }
    *(v8h*)pA = uA;
    *(v8h*)pB = uB;
  }

  // incremental gradV, interleaved with backward (arena reuse)
  v4f aGA = (v4f){0.f,0.f,0.f,0.f};
  v4f aGB = (v4f){0.f,0.f,0.f,0.f};

  gacc2(aGA, aGB, g_w16 + OFF_V3XT, ZA3, ZB3, lm, q);             // L3 (ga3=u3)
  vbwd2(ZA3, ZA2, ZB3, ZB2, g_w16 + OFF_V3ZT, lm, q);             // ga2 -> Z2
  gacc2(aGA, aGB, g_w16 + OFF_V2XT, ZA2, ZB2, lm, q);             // L2
  vbwd2_l1(ZA2, ZB2, g_w16 + OFF_V2ZT, g_w16 + OFF_VL1T,
           dA0, dA1, dB0, dB1, lm, q);                            // ga1 -> Z2
  gacc2(aGA, aGB, g_w16 + OFF_VL1T, ZA2, ZB2, lm, q);             // L1

  const float g0A = fmaf(0.02f, dA0, sfA * (vfx0 + aGA[0]));
  const float g1A = fmaf(0.02f, dA1, sfA * (vfx1 + aGA[1]));
  const float g0B = fmaf(0.02f, dB0, sfB * (vfx0 + aGB[0]));
  const float g1B = fmaf(0.02f, dB1, sfB * (vfx1 + aGB[1]));

  if (q == 0){
    if (rowA < NPTS) g_grad[rowA] = make_float4(g0A, g1A, VVrA, 0.f);
    if (rowB < NPTS) g_grad[rowB] = make_float4(g0B, g1B, VVrB, 0.f);
  }
}

// ================= fused heterogeneous kernel =================
__global__ __launch_bounds__(256, 4) void fused_kernel(
  const float* __restrict__ X, const float* __restrict__ Xst,
  const float* __restrict__ Vfx,
  const float* __restrict__ f1b, const float* __restrict__ f2b,
  const float* __restrict__ f3b, const float* __restrict__ f4b,
  const float* __restrict__ f5b, const float* __restrict__ ffb)
{
  __shared__ __align__(16) char smem[32768];   // fhat H 128x128 | vnet 4x8KB
  const int g = blockIdx.x;
  if ((g & 1) == 0){
    fhat_body(g >> 1, (_Float16*)smem, X, f1b, f2b, f3b, f4b, f5b, ffb);
  } else {
    vnet_body2(g >> 1, smem, X, Xst, Vfx);
  }
}

// ================= combine epilogue (2 rows/thread, ~16 MB) =================
__global__ __launch_bounds__(256) void combine_kernel(float* __restrict__ out)
{
  const int idx = blockIdx.x * 256 + threadIdx.x;
  const int i0 = idx * 2;
  if (i0 >= NPTS) return;
  const float4 fh2 = *(const float4*)(g_fh + i0*2);
  const float4 ga = g_grad[i0];
  const float4 gb = g_grad[i0 + 1];
  float4 o;
  {
    const float Vn  = fmaf(ga.x, ga.x, ga.y*ga.y);
    const float num = fmaf(0.1f, ga.z, fmaf(fh2.x, ga.x, fh2.y*ga.y));
    const float fm  = fmaxf(num, 0.f) / (Vn + 1e-10f);
    o.x = fmaf(-ga.x, fm, fh2.x);
    o.y = fmaf(-ga.y, fm, fh2.y);
  }
  {
    const float Vn  = fmaf(gb.x, gb.x, gb.y*gb.y);
    const float num = fmaf(0.1f, gb.z, fmaf(fh2.z, gb.x, fh2.w*gb.y));
    const float fm  = fmaxf(num, 0.f) / (Vn + 1e-10f);
    o.z = fmaf(-gb.x, fm, fh2.z);
    o.w = fmaf(-gb.y, fm, fh2.w);
  }
  *(float4*)(out + i0*2) = o;
}

extern "C" void kernel_launch(void* const* d_in, const int* in_sizes, int n_in,
                              void* d_out, int out_size, void* d_ws, size_t ws_size,
                              hipStream_t stream)
{
  (void)d_ws; (void)ws_size; (void)n_in; (void)in_sizes; (void)out_size;
  const float* X   = (const float*)d_in[0];
  const float* Xst = (const float*)d_in[1];
  const float* Vl1 = (const float*)d_in[2];
  const float* V2x = (const float*)d_in[3];
  const float* V2z = (const float*)d_in[4];
  const float* V3x = (const float*)d_in[5];
  const float* V3z = (const float*)d_in[6];
  const float* Vfx = (const float*)d_in[7];
  const float* Vfz = (const float*)d_in[8];
  const float* f1w = (const float*)d_in[9];
  const float* f1b = (const float*)d_in[10];
  const float* f2w = (const float*)d_in[11];
  const float* f2b = (const float*)d_in[12];
  const float* f3w = (const float*)d_in[13];
  const float* f3b = (const float*)d_in[14];
  const float* f4w = (const float*)d_in[15];
  const float* f4b = (const float*)d_in[16];
  const float* f5w = (const float*)d_in[17];
  const float* f5b = (const float*)d_in[18];
  const float* ffw = (const float*)d_in[19];
  const float* ffb = (const float*)d_in[20];

  prep_kernel<<<(W16_TOTAL + 255)/256, 256, 0, stream>>>(
      f2w, f3w, f4w, f5w, V2z, V3z, Vl1, V2x, V3x, Vfz, ffw, f1w);
  fused_kernel<<<FUSED_GRID, 256, 0, stream>>>(
      X, Xst, Vfx, f1b, f2b, f3b, f4b, f5b, ffb);
  combine_kernel<<<(NPTS/2 + 255)/256, 256, 0, stream>>>((float*)d_out);
}

// Round 4
// 270.996 us; speedup vs baseline: 2.3008x; 1.0059x over previous
//
#include <hip/hip_runtime.h>

// ICNN_net_1503238553972 — round 22: MERGED fhat+vnet+combine.
// R21 (272.6us total, 209us fused) validated the structure. The ~64us
// total-vs-fused gap is prep+combine+launch overhead. Key insight: fhat
// wave w and vnet wave w of block b own the SAME rows (b*128+w*32+lm,
// +16), and the ff tail + vnet arenas touch only the wave's own 8KB H
// slice. So one block runs fhat phase -> ff (results stay in regs) ->
// vnet phase (wave-local, barrier-free) -> combine in regs -> store out.
// Deletes combine_kernel, g_fh, g_grad (24MB round-trip) and one launch.
// fhat/vnet instruction streams identical to R21. Grid 3907,
// launch_bounds(256,4), LDS 32KB.

typedef _Float16 v2h __attribute__((ext_vector_type(2)));
typedef __fp16   v2hf __attribute__((ext_vector_type(2)));
typedef _Float16 v4h __attribute__((ext_vector_type(4)));
typedef _Float16 v8h __attribute__((ext_vector_type(8)));
typedef float    v4f __attribute__((ext_vector_type(4)));

__device__ __forceinline__ v2h cvt_pk(float a, float b){
  v2hf r = __builtin_amdgcn_cvt_pkrtz(a, b);
  union { v2hf f; v2h h; } u; u.f = r;
  return u.h;
}

#define NPTS 500000
#define FUSED_GRID ((NPTS + 127) / 128)   // 3907

// LDS-only barrier: LDS ordering without draining vmcnt (weights in flight)
#define BAR_LDS() asm volatile("s_waitcnt lgkmcnt(0)\n\ts_barrier" ::: "memory")

// offsets in halves inside g_w16
#define OFF_FW    0               // f2..f5: L*16384, [o*128+k]
#define OFF_V2Z   65536           // [j*64+k]
#define OFF_V3Z   69632
#define OFF_V2ZT  73728           // [k*64+j]
#define OFF_V3ZT  77824
#define OFF_VL1T  81920           // [c*64+j]
#define OFF_V2XT  82048
#define OFF_V3XT  82176
#define OFF_VFZ   82304           // [64]
#define OFF_FFW   82368           // [c*128+k]
#define OFF_F1W   82624           // [oc*2+c]
#define OFF_F1P   82880           // f1 padded [o*32+k], k<2 valid else 0
#define W16_DATA  86976
#define W16_TOTAL (W16_DATA + 2048)   // zero pad: junk A-rows stay in-bounds

__device__ __align__(16) _Float16 g_w16[W16_TOTAL];

__device__ __forceinline__ float srelu(float x){
  float c = fminf(fmaxf(x, 0.f), 1.f);
  return c * fmaf(-0.5f, c, x);
}
__device__ __forceinline__ float sreluD(float x){
  return fminf(fmaxf(x, 0.f), 1.f);
}
__device__ __forceinline__ float sreluD_from_z(float z){
  return fminf(sqrtf(2.f * z), 1.f);
}

// ---- packed f16 activations (2 f32 in -> 2 f16 out) ----
__device__ __forceinline__ v2h lrelu_pk(float a, float b){
  v2h x = cvt_pk(a, b);
  v2h m = x * (v2h){(_Float16)0.01f, (_Float16)0.01f};
  return __builtin_elementwise_max(x, m);
}
__device__ __forceinline__ v2h srelu_pk(float a, float b){
  v2h x = cvt_pk(a, b);
  const v2h z0 = (v2h){(_Float16)0.f, (_Float16)0.f};
  const v2h o1 = (v2h){(_Float16)1.f, (_Float16)1.f};
  const v2h hf = (v2h){(_Float16)0.5f, (_Float16)0.5f};
  v2h c = __builtin_elementwise_min(__builtin_elementwise_max(x, z0), o1);
  v2h t = x - c * hf;
  return c * t;
}

// ---------------- prep: fp32 weights -> f16 layouts (+zero pad) ----------------
__global__ __launch_bounds__(256) void prep_kernel(
  const float* __restrict__ f2w, const float* __restrict__ f3w,
  const float* __restrict__ f4w, const float* __restrict__ f5w,
  const float* __restrict__ V2z, const float* __restrict__ V3z,
  const float* __restrict__ Vl1, const float* __restrict__ V2x,
  const float* __restrict__ V3x, const float* __restrict__ Vfz,
  const float* __restrict__ ffw, const float* __restrict__ f1w)
{
  const int i = blockIdx.x * 256 + threadIdx.x;
  if (i >= W16_TOTAL) return;
  if (i >= W16_DATA){ g_w16[i] = (_Float16)0.f; return; }
  float v;
  if (i < 65536){
    const float* W[4] = {f2w, f3w, f4w, f5w};
    v = W[i >> 14][i & 16383];
  } else if (i < 69632)  v = V2z[i - 65536];
  else if (i < 73728)    v = V3z[i - 69632];
  else if (i < 77824){ int r = i - 73728; v = V2z[(r & 63)*64 + (r >> 6)]; }
  else if (i < 81920){ int r = i - 77824; v = V3z[(r & 63)*64 + (r >> 6)]; }
  else if (i < 82048){ int r = i - 81920; v = Vl1[(r & 63)*2 + (r >> 6)]; }
  else if (i < 82176){ int r = i - 82048; v = V2x[(r & 63)*2 + (r >> 6)]; }
  else if (i < 82304){ int r = i - 82176; v = V3x[(r & 63)*2 + (r >> 6)]; }
  else if (i < 82368)    v = Vfz[i - 82304];
  else if (i < 82624)    v = ffw[i - 82368];
  else if (i < 82880)    v = f1w[i - 82624];
  else { int r = i - 82880; int k = r & 31; v = (k < 2) ? f1w[(r >> 5)*2 + k] : 0.f; }
  g_w16[i] = (_Float16)v;
}

// ================= fhat layer: 256 thr, 128 rows (R21 form) =================
__device__ __forceinline__ void fh_layer(_Float16* H,
    const _Float16* __restrict__ Wl, const float* __restrict__ Bp,
    int w, int lm, int q)
{
  // bias as MFMA C-init: acc reg r holds output feature o0+r, uniform over
  // lanes' col and nt — exact same math as post-add.
  const v4f bva = *(const v4f*)(Bp + w*32 + q*4);
  const v4f bvb = *(const v4f*)(Bp + w*32 + 16 + q*4);
  v4f acc[2][8];
#pragma unroll
  for (int nt = 0; nt < 8; ++nt){
    acc[0][nt] = bva;
    acc[1][nt] = bvb;
  }

#pragma unroll
  for (int kt = 0; kt < 4; ++kt){
    const int sw = ((kt*4 + q) ^ lm) << 3;
    v8h A0 = *(const v8h*)(Wl + (w*32      + lm)*128 + kt*32 + q*8);
    v8h A1 = *(const v8h*)(Wl + (w*32 + 16 + lm)*128 + kt*32 + q*8);
#pragma unroll
    for (int nt = 0; nt < 8; ++nt){
      v8h B = *(const v8h*)(H + (nt*16 + lm)*128 + sw);
      acc[0][nt] = __builtin_amdgcn_mfma_f32_16x16x32_f16(A0, B, acc[0][nt], 0,0,0);
      acc[1][nt] = __builtin_amdgcn_mfma_f32_16x16x32_f16(A1, B, acc[1][nt], 0,0,0);
    }
  }
  BAR_LDS();
#pragma unroll
  for (int mt = 0; mt < 2; ++mt){
    const int o0 = w*32 + mt*16 + q*4;
    const int coff = (((o0 >> 3) ^ lm) << 3) + (o0 & 7);
#pragma unroll
    for (int nt = 0; nt < 8; ++nt){
      v4h hv;
      *(v2h*)&hv       = lrelu_pk(acc[mt][nt][0], acc[mt][nt][1]);
      *((v2h*)&hv + 1) = lrelu_pk(acc[mt][nt][2], acc[mt][nt][3]);
      *(v4h*)(H + (nt*16 + lm)*128 + coff) = hv;
    }
  }
  BAR_LDS();
}

// ================= vnet pieces (R21/R18 ILP-2 form, barrier-free) =================
__device__ __forceinline__ void vfwd2_l2(_Float16* zoutA, _Float16* zoutB,
    const _Float16* __restrict__ Wz,   // V2Z [o][k]
    const _Float16* __restrict__ WxT,  // V2XT [2][64]
    const _Float16* __restrict__ Wl1T, // VL1T [2][64]
    float dA0, float dA1, float dB0, float dB1, int lm, int q)
{
  v4f accA[4], accB[4];
#pragma unroll
  for (int mt = 0; mt < 4; ++mt){
    accA[mt] = (v4f){0.f,0.f,0.f,0.f};
    accB[mt] = (v4f){0.f,0.f,0.f,0.f};
  }
  const int rs = lm & 7;
#pragma unroll
  for (int kt = 0; kt < 2; ++kt){
    v8h w0 = *(const v8h*)(Wl1T + kt*32 + q*8);
    v8h w1 = *(const v8h*)(Wl1T + 64 + kt*32 + q*8);
    v8h BA, BB;
#pragma unroll
    for (int j2 = 0; j2 < 4; ++j2){
      const float a0 = (float)w0[2*j2  ], a1 = (float)w0[2*j2+1];
      const float c0 = (float)w1[2*j2  ], c1 = (float)w1[2*j2+1];
      ((v2h*)&BA)[j2] = srelu_pk(fmaf(dA0,a0,dA1*c0), fmaf(dA0,a1,dA1*c1));
      ((v2h*)&BB)[j2] = srelu_pk(fmaf(dB0,a0,dB1*c0), fmaf(dB0,a1,dB1*c1));
    }
#pragma unroll
    for (int mt = 0; mt < 4; ++mt){
      v8h A = *(const v8h*)(Wz + (mt*16 + lm)*64 + kt*32 + q*8);
      accA[mt] = __builtin_amdgcn_mfma_f32_16x16x32_f16(A, BA, accA[mt], 0,0,0);
      accB[mt] = __builtin_amdgcn_mfma_f32_16x16x32_f16(A, BB, accB[mt], 0,0,0);
    }
  }
#pragma unroll
  for (int mt = 0; mt < 4; ++mt){
    const int o0 = mt*16 + q*4;
    const int off = (((o0 >> 3) ^ rs) << 3) + (o0 & 7);
    float vA[4], vB[4];
#pragma unroll
    for (int reg = 0; reg < 4; ++reg){
      const float wx0 = (float)WxT[o0 + reg];
      const float wx1 = (float)WxT[64 + o0 + reg];
      vA[reg] = accA[mt][reg] + wx0*dA0 + wx1*dA1;
      vB[reg] = accB[mt][reg] + wx0*dB0 + wx1*dB1;
    }
    v4h hA, hB;
    *(v2h*)&hA       = srelu_pk(vA[0], vA[1]);
    *((v2h*)&hA + 1) = srelu_pk(vA[2], vA[3]);
    *(v2h*)&hB       = srelu_pk(vB[0], vB[1]);
    *((v2h*)&hB + 1) = srelu_pk(vB[2], vB[3]);
    *(v4h*)(zoutA + lm*64 + off) = hA;
    *(v4h*)(zoutB + lm*64 + off) = hB;
  }
}

__device__ __forceinline__ void vfwd2(const _Float16* zinA, _Float16* zoutA,
    const _Float16* zinB, _Float16* zoutB,
    const _Float16* __restrict__ Wz, const _Float16* __restrict__ WxT,
    float dA0, float dA1, float dB0, float dB1, int lm, int q)
{
  v4f accA[4], accB[4];
#pragma unroll
  for (int mt = 0; mt < 4; ++mt){
    accA[mt] = (v4f){0.f,0.f,0.f,0.f};
    accB[mt] = (v4f){0.f,0.f,0.f,0.f};
  }
  const int rs = lm & 7;
#pragma unroll
  for (int kt = 0; kt < 2; ++kt){
    const int sw = (((kt*4 + q) ^ rs) << 3);
    v8h BA = *(const v8h*)(zinA + lm*64 + sw);
    v8h BB = *(const v8h*)(zinB + lm*64 + sw);
#pragma unroll
    for (int mt = 0; mt < 4; ++mt){
      v8h A = *(const v8h*)(Wz + (mt*16 + lm)*64 + kt*32 + q*8);
      accA[mt] = __builtin_amdgcn_mfma_f32_16x16x32_f16(A, BA, accA[mt], 0,0,0);
      accB[mt] = __builtin_amdgcn_mfma_f32_16x16x32_f16(A, BB, accB[mt], 0,0,0);
    }
  }
#pragma unroll
  for (int mt = 0; mt < 4; ++mt){
    const int o0 = mt*16 + q*4;
    const int off = (((o0 >> 3) ^ rs) << 3) + (o0 & 7);
    float vA[4], vB[4];
#pragma unroll
    for (int reg = 0; reg < 4; ++reg){
      const float wx0 = (float)WxT[o0 + reg];
      const float wx1 = (float)WxT[64 + o0 + reg];
      vA[reg] = accA[mt][reg] + wx0*dA0 + wx1*dA1;
      vB[reg] = accB[mt][reg] + wx0*dB0 + wx1*dB1;
    }
    v4h hA, hB;
    *(v2h*)&hA       = srelu_pk(vA[0], vA[1]);
    *((v2h*)&hA + 1) = srelu_pk(vA[2], vA[3]);
    *(v2h*)&hB       = srelu_pk(vB[0], vB[1]);
    *((v2h*)&hB + 1) = srelu_pk(vB[2], vB[3]);
    *(v4h*)(zoutA + lm*64 + off) = hA;
    *(v4h*)(zoutB + lm*64 + off) = hB;
  }
}

__device__ __forceinline__ void vbwd2(const _Float16* ginA, _Float16* zioA,
    const _Float16* ginB, _Float16* zioB,
    const _Float16* __restrict__ WT, int lm, int q)
{
  v4f accA[4], accB[4];
#pragma unroll
  for (int mt = 0; mt < 4; ++mt){
    accA[mt] = (v4f){0.f,0.f,0.f,0.f};
    accB[mt] = (v4f){0.f,0.f,0.f,0.f};
  }
  const int rs = lm & 7;
#pragma unroll
  for (int kt = 0; kt < 2; ++kt){
    const int sw = (((kt*4 + q) ^ rs) << 3);
    v8h BA = *(const v8h*)(ginA + lm*64 + sw);
    v8h BB = *(const v8h*)(ginB + lm*64 + sw);
#pragma unroll
    for (int mt = 0; mt < 4; ++mt){
      v8h A = *(const v8h*)(WT + (mt*16 + lm)*64 + kt*32 + q*8);
      accA[mt] = __builtin_amdgcn_mfma_f32_16x16x32_f16(A, BA, accA[mt], 0,0,0);
      accB[mt] = __builtin_amdgcn_mfma_f32_16x16x32_f16(A, BB, accB[mt], 0,0,0);
    }
  }
#pragma unroll
  for (int mt = 0; mt < 4; ++mt){
    const int k0 = mt*16 + q*4;
    const int off = (((k0 >> 3) ^ rs) << 3) + (k0 & 7);
    _Float16* pA = zioA + lm*64 + off;
    _Float16* pB = zioB + lm*64 + off;
    v4h zA = *(const v4h*)pA;
    v4h zB = *(const v4h*)pB;
    float sA0 = accA[mt][0] * sreluD_from_z((float)zA[0]);
    float sA1 = accA[mt][1] * sreluD_from_z((float)zA[1]);
    float sA2 = accA[mt][2] * sreluD_from_z((float)zA[2]);
    float sA3 = accA[mt][3] * sreluD_from_z((float)zA[3]);
    float sB0 = accB[mt][0] * sreluD_from_z((float)zB[0]);
    float sB1 = accB[mt][1] * sreluD_from_z((float)zB[1]);
    float sB2 = accB[mt][2] * sreluD_from_z((float)zB[2]);
    float sB3 = accB[mt][3] * sreluD_from_z((float)zB[3]);
    v4h gA, gB;
    *(v2h*)&gA       = cvt_pk(sA0, sA1);
    *((v2h*)&gA + 1) = cvt_pk(sA2, sA3);
    *(v2h*)&gB       = cvt_pk(sB0, sB1);
    *((v2h*)&gB + 1) = cvt_pk(sB2, sB3);
    *(v4h*)pA = gA;
    *(v4h*)pB = gB;
  }
}

__device__ __forceinline__ void vbwd2_l1(_Float16* zioA, _Float16* zioB,
    const _Float16* __restrict__ WT,   // V2ZT
    const _Float16* __restrict__ Wl1T, // VL1T [2][64]
    float dA0, float dA1, float dB0, float dB1, int lm, int q)
{
  v4f accA[4], accB[4];
#pragma unroll
  for (int mt = 0; mt < 4; ++mt){
    accA[mt] = (v4f){0.f,0.f,0.f,0.f};
    accB[mt] = (v4f){0.f,0.f,0.f,0.f};
  }
  const int rs = lm & 7;
#pragma unroll
  for (int kt = 0; kt < 2; ++kt){
    const int sw = (((kt*4 + q) ^ rs) << 3);
    v8h BA = *(const v8h*)(zioA + lm*64 + sw);
    v8h BB = *(const v8h*)(zioB + lm*64 + sw);
#pragma unroll
    for (int mt = 0; mt < 4; ++mt){
      v8h A = *(const v8h*)(WT + (mt*16 + lm)*64 + kt*32 + q*8);
      accA[mt] = __builtin_amdgcn_mfma_f32_16x16x32_f16(A, BA, accA[mt], 0,0,0);
      accB[mt] = __builtin_amdgcn_mfma_f32_16x16x32_f16(A, BB, accB[mt], 0,0,0);
    }
  }
#pragma unroll
  for (int mt = 0; mt < 4; ++mt){
    const int k0 = mt*16 + q*4;
    const int off = (((k0 >> 3) ^ rs) << 3) + (k0 & 7);
    v4h w0 = *(const v4h*)(Wl1T + k0);
    v4h w1 = *(const v4h*)(Wl1T + 64 + k0);
    float sA[4], sB[4];
#pragma unroll
    for (int reg = 0; reg < 4; ++reg){
      const float a1A = fmaf(dA0, (float)w0[reg], dA1 * (float)w1[reg]);
      const float a1B = fmaf(dB0, (float)w0[reg], dB1 * (float)w1[reg]);
      sA[reg] = accA[mt][reg] * sreluD(a1A);
      sB[reg] = accB[mt][reg] * sreluD(a1B);
    }
    v4h gA, gB;
    *(v2h*)&gA       = cvt_pk(sA[0], sA[1]);
    *((v2h*)&gA + 1) = cvt_pk(sA[2], sA[3]);
    *(v2h*)&gB       = cvt_pk(sB[0], sB[1]);
    *((v2h*)&gB + 1) = cvt_pk(sB[2], sB[3]);
    *(v4h*)(zioA + lm*64 + off) = gA;
    *(v4h*)(zioB + lm*64 + off) = gB;
  }
}

__device__ __forceinline__ void gacc2(v4f& aGA, v4f& aGB,
    const _Float16* __restrict__ WxTbase,
    const _Float16* ZA, const _Float16* ZB, int lm, int q)
{
  const int rs = lm & 7;
#pragma unroll
  for (int kt = 0; kt < 2; ++kt){
    const int sw = (((kt*4 + q) ^ rs) << 3);
    v8h A  = *(const v8h*)(WxTbase + lm*64 + kt*32 + q*8);
    v8h BA = *(const v8h*)(ZA + lm*64 + sw);
    v8h BB = *(const v8h*)(ZB + lm*64 + sw);
    aGA = __builtin_amdgcn_mfma_f32_16x16x32_f16(A, BA, aGA, 0,0,0);
    aGB = __builtin_amdgcn_mfma_f32_16x16x32_f16(A, BB, aGB, 0,0,0);
  }
}

// ================= merged kernel: fhat -> ff(regs) -> vnet -> combine =================
__global__ __launch_bounds__(256, 4) void fused_kernel(
  const float* __restrict__ X, const float* __restrict__ Xst,
  const float* __restrict__ Vfx,
  const float* __restrict__ f1b, const float* __restrict__ f2b,
  const float* __restrict__ f3b, const float* __restrict__ f4b,
  const float* __restrict__ f5b, const float* __restrict__ ffb,
  float* __restrict__ out)
{
  __shared__ __align__(16) char smem[32768];   // fhat H 128x128 | vnet 4x8KB/wave
  _Float16* const H = (_Float16*)smem;

  const int b  = blockIdx.x;
  const int t  = threadIdx.x;
  const int w  = t >> 6;
  const int l  = t & 63;
  const int lm = l & 15;
  const int q  = l >> 4;
  const int rs = lm & 7;
  const int row0 = b*128 + w*32;

  const int r0 = row0 + lm;
  const int r1 = row0 + 16 + lm;
  const int rc0 = r0 < NPTS ? r0 : NPTS-1;
  const int rc1 = r1 < NPTS ? r1 : NPTS-1;
  const float2 x0 = *(const float2*)(X + rc0*2);
  const float2 x1 = *(const float2*)(X + rc1*2);

  // ========== fhat phase ==========
  // ---- f1 via MFMA: A = f1w padded to K=32, B = x (q==0 lanes k=0,1) ----
  {
    v8h Bx0 = (v8h){(_Float16)0.f,(_Float16)0.f,(_Float16)0.f,(_Float16)0.f,
                    (_Float16)0.f,(_Float16)0.f,(_Float16)0.f,(_Float16)0.f};
    v8h Bx1 = Bx0;
    if (q == 0){
      Bx0[0] = (_Float16)x0.x; Bx0[1] = (_Float16)x0.y;
      Bx1[0] = (_Float16)x1.x; Bx1[1] = (_Float16)x1.y;
    }
#pragma unroll
    for (int mt = 0; mt < 8; ++mt){
      const int o0 = mt*16 + q*4;
      const v4f bv = *(const v4f*)(f1b + o0);
      v8h A = *(const v8h*)(g_w16 + OFF_F1P + (mt*16 + lm)*32 + q*8);
      v4f a0 = __builtin_amdgcn_mfma_f32_16x16x32_f16(A, Bx0, bv, 0,0,0);
      v4f a1 = __builtin_amdgcn_mfma_f32_16x16x32_f16(A, Bx1, bv, 0,0,0);
      const int coff = (((o0 >> 3) ^ lm) << 3) + (o0 & 7);
      v4h h0, h1;
      *(v2h*)&h0       = lrelu_pk(a0[0], a0[1]);
      *((v2h*)&h0 + 1) = lrelu_pk(a0[2], a0[3]);
      *(v2h*)&h1       = lrelu_pk(a1[0], a1[1]);
      *((v2h*)&h1 + 1) = lrelu_pk(a1[2], a1[3]);
      *(v4h*)(H + (w*32 + lm)*128 + coff)      = h0;
      *(v4h*)(H + (w*32 + 16 + lm)*128 + coff) = h1;
    }
  }
  BAR_LDS();

  fh_layer(H, g_w16 + OFF_FW,         f2b, w, lm, q);
  fh_layer(H, g_w16 + OFF_FW + 16384, f3b, w, lm, q);
  fh_layer(H, g_w16 + OFF_FW + 32768, f4b, w, lm, q);
  fh_layer(H, g_w16 + OFF_FW + 49152, f5b, w, lm, q);

  // ---- ff via MFMA on the wave's OWN rows (H slice [w*8192, +8192)) ----
  // Results stay in registers (valid on q==0 lanes).
  float fhA0, fhA1, fhB0, fhB1;
  {
    v4f a0 = (v4f){0.f,0.f,0.f,0.f};
    v4f a1 = (v4f){0.f,0.f,0.f,0.f};
#pragma unroll
    for (int kt = 0; kt < 4; ++kt){
      const int sw = ((kt*4 + q) ^ lm) << 3;
      v8h A  = *(const v8h*)(g_w16 + OFF_FFW + lm*128 + kt*32 + q*8);
      v8h B0 = *(const v8h*)(H + (w*32 + lm)*128 + sw);
      v8h B1 = *(const v8h*)(H + (w*32 + 16 + lm)*128 + sw);
      a0 = __builtin_amdgcn_mfma_f32_16x16x32_f16(A, B0, a0, 0,0,0);
      a1 = __builtin_amdgcn_mfma_f32_16x16x32_f16(A, B1, a1, 0,0,0);
    }
    const float fb0 = ffb[0], fb1 = ffb[1];
    fhA0 = a0[0] + fb0; fhA1 = a0[1] + fb1;
    fhB0 = a1[0] + fb0; fhB1 = a1[1] + fb1;
  }

  // ========== vnet phase (wave-local slice; no barrier needed: after f5's
  // trailing barrier only the owning wave touches its own 8KB slice) ==========
  _Float16* const ZA2 = (_Float16*)(smem + w*8192);
  _Float16* const ZA3 = ZA2 + 1024;
  _Float16* const ZB2 = ZA2 + 2048;
  _Float16* const ZB3 = ZA2 + 3072;

  const float2 sA = *(const float2*)(Xst + rc0*2);
  const float2 sB = *(const float2*)(Xst + rc1*2);
  const float dA0 = x0.x - sA.x, dA1 = x0.y - sA.y;
  const float dB0 = x1.x - sB.x, dB1 = x1.y - sB.y;
  const float vfx0 = Vfx[0], vfx1 = Vfx[1];

  // fwd: z2 (z1 in registers), z3
  vfwd2_l2(ZA2, ZB2, g_w16 + OFF_V2Z, g_w16 + OFF_V2XT, g_w16 + OFF_VL1T,
           dA0, dA1, dB0, dB1, lm, q);
  vfwd2(ZA2, ZA3, ZB2, ZB3, g_w16 + OFF_V3Z, g_w16 + OFF_V3XT,
        dA0, dA1, dB0, dB1, lm, q);

  // zf head for both (A row 0 = Vfz)
  float VVrA, sfA, VVrB, sfB;
  {
    v4f aSA = (v4f){0.f,0.f,0.f,0.f};
    v4f aSB = (v4f){0.f,0.f,0.f,0.f};
#pragma unroll
    for (int kt = 0; kt < 2; ++kt){
      const int sw = (((kt*4 + q) ^ rs) << 3);
      v8h A  = *(const v8h*)(g_w16 + OFF_VFZ + lm*64 + kt*32 + q*8);
      v8h BA = *(const v8h*)(ZA3 + lm*64 + sw);
      v8h BB = *(const v8h*)(ZB3 + lm*64 + sw);
      aSA = __builtin_amdgcn_mfma_f32_16x16x32_f16(A, BA, aSA, 0,0,0);
      aSB = __builtin_amdgcn_mfma_f32_16x16x32_f16(A, BB, aSB, 0,0,0);
    }
    const float afA = fmaf(vfx0, dA0, fmaf(vfx1, dA1, aSA[0]));
    const float zfA = srelu(afA);
    VVrA = srelu(zfA) + 0.01f * fmaf(dA0, dA0, dA1*dA1);
    sfA  = sreluD(zfA) * sreluD(afA);
    const float afB = fmaf(vfx0, dB0, fmaf(vfx1, dB1, aSB[0]));
    const float zfB = srelu(afB);
    VVrB = srelu(zfB) + 0.01f * fmaf(dB0, dB0, dB1*dB1);
    sfB  = sreluD(zfB) * sreluD(afB);
  }

  // u3 = Vfz * srelu'(a3) (sf deferred; in place over Z3)
#pragma unroll
  for (int cc = 0; cc < 2; ++cc){
    const int c = q*2 + cc;
    const int sw = ((c ^ rs) << 3);
    v8h vf = *(const v8h*)(g_w16 + OFF_VFZ + c*8);
    _Float16* pA = ZA3 + lm*64 + sw;
    _Float16* pB = ZB3 + lm*64 + sw;
    v8h zA = *(const v8h*)pA;
    v8h zB = *(const v8h*)pB;
    v8h uA, uB;
#pragma unroll
    for (int j2 = 0; j2 < 4; ++j2){
      float a0 = (float)vf[2*j2  ] * sreluD_from_z((float)zA[2*j2  ]);
      float a1 = (float)vf[2*j2+1] * sreluD_from_z((float)zA[2*j2+1]);
      float b0 = (float)vf[2*j2  ] * sreluD_from_z((float)zB[2*j2  ]);
      float b1 = (float)vf[2*j2+1] * sreluD_from_z((float)zB[2*j2+1]);
      ((v2h*)&uA)[j2] = cvt_pk(a0, a1);
      ((v2h*)&uB)[j2] = cvt_pk(b0, b1);
    }
    *(v8h*)pA = uA;
    *(v8h*)pB = uB;
  }

  // incremental gradV, interleaved with backward (arena reuse)
  v4f aGA = (v4f){0.f,0.f,0.f,0.f};
  v4f aGB = (v4f){0.f,0.f,0.f,0.f};

  gacc2(aGA, aGB, g_w16 + OFF_V3XT, ZA3, ZB3, lm, q);             // L3 (ga3=u3)
  vbwd2(ZA3, ZA2, ZB3, ZB2, g_w16 + OFF_V3ZT, lm, q);             // ga2 -> Z2
  gacc2(aGA, aGB, g_w16 + OFF_V2XT, ZA2, ZB2, lm, q);             // L2
  vbwd2_l1(ZA2, ZB2, g_w16 + OFF_V2ZT, g_w16 + OFF_VL1T,
           dA0, dA1, dB0, dB1, lm, q);                            // ga1 -> Z2
  gacc2(aGA, aGB, g_w16 + OFF_VL1T, ZA2, ZB2, lm, q);             // L1

  const float g0A = fmaf(0.02f, dA0, sfA * (vfx0 + aGA[0]));
  const float g1A = fmaf(0.02f, dA1, sfA * (vfx1 + aGA[1]));
  const float g0B = fmaf(0.02f, dB0, sfB * (vfx0 + aGB[0]));
  const float g1B = fmaf(0.02f, dB1, sfB * (vfx1 + aGB[1]));

  // ========== combine in registers, store out ==========
  if (q == 0){
    if (r0 < NPTS){
      const float Vn  = fmaf(g0A, g0A, g1A*g1A);
      const float num = fmaf(0.1f, VVrA, fmaf(fhA0, g0A, fhA1*g1A));
      const float fm  = fmaxf(num, 0.f) / (Vn + 1e-10f);
      *(float2*)(out + r0*2) =
        make_float2(fmaf(-g0A, fm, fhA0), fmaf(-g1A, fm, fhA1));
    }
    if (r1 < NPTS){
      const float Vn  = fmaf(g0B, g0B, g1B*g1B);
      const float num = fmaf(0.1f, VVrB, fmaf(fhB0, g0B, fhB1*g1B));
      const float fm  = fmaxf(num, 0.f) / (Vn + 1e-10f);
      *(float2*)(out + r1*2) =
        make_float2(fmaf(-g0B, fm, fhB0), fmaf(-g1B, fm, fhB1));
    }
  }
}

extern "C" void kernel_launch(void* const* d_in, const int* in_sizes, int n_in,
                              void* d_out, int out_size, void* d_ws, size_t ws_size,
                              hipStream_t stream)
{
  (void)d_ws; (void)ws_size; (void)n_in; (void)in_sizes; (void)out_size;
  const float* X   = (const float*)d_in[0];
  const float* Xst = (const float*)d_in[1];
  const float* Vl1 = (const float*)d_in[2];
  const float* V2x = (const float*)d_in[3];
  const float* V2z = (const float*)d_in[4];
  const float* V3x = (const float*)d_in[5];
  const float* V3z = (const float*)d_in[6];
  const float* Vfx = (const float*)d_in[7];
  const float* Vfz = (const float*)d_in[8];
  const float* f1w = (const float*)d_in[9];
  const float* f1b = (const float*)d_in[10];
  const float* f2w = (const float*)d_in[11];
  const float* f2b = (const float*)d_in[12];
  const float* f3w = (const float*)d_in[13];
  const float* f3b = (const float*)d_in[14];
  const float* f4w = (const float*)d_in[15];
  const float* f4b = (const float*)d_in[16];
  const float* f5w = (const float*)d_in[17];
  const float* f5b = (const float*)d_in[18];
  const float* ffw = (const float*)d_in[19];
  const float* ffb = (const float*)d_in[20];

  prep_kernel<<<(W16_TOTAL + 255)/256, 256, 0, stream>>>(
      f2w, f3w, f4w, f5w, V2z, V3z, Vl1, V2x, V3x, Vfz, ffw, f1w);
  fused_kernel<<<FUSED_GRID, 256, 0, stream>>>(
      X, Xst, Vfx, f1b, f2b, f3b, f4b, f5b, ffb, (float*)d_out);
}

// Round 5
// 256.210 us; speedup vs baseline: 2.4336x; 1.0577x over previous
//
#include <hip/hip_runtime.h>

// ICNN_net_1503238553972 — round 23: 256-row / 512-thread blocks.
// R22 (merged, 200.8us fused) left ~40-50% idle concentrated at the 10
// block-wide barriers per 128 rows. This round doubles rows per block
// with the per-row instruction stream UNCHANGED (R19's failure was
// per-row overhead doubling — absent here):
//   - H = 256x128 f16 = 64KB; 8 waves; wave w owns feats [w*16,w*16+16)
//     over all 256 rows -> acc[16], ONE A-frag shared by 16 MFMAs.
//   - Barriers per row HALVED (10 per 256 rows); TLP unchanged
//     (2 blocks/CU x 8 waves = 4 waves/SIMD).
//   - f1/ff/vnet per-wave bodies identical (row0 = b*256 + w*32);
//     vnet arenas 8x8KB reuse H. launch_bounds(512,4), grid 1954.

typedef _Float16 v2h __attribute__((ext_vector_type(2)));
typedef __fp16   v2hf __attribute__((ext_vector_type(2)));
typedef _Float16 v4h __attribute__((ext_vector_type(4)));
typedef _Float16 v8h __attribute__((ext_vector_type(8)));
typedef float    v4f __attribute__((ext_vector_type(4)));

__device__ __forceinline__ v2h cvt_pk(float a, float b){
  v2hf r = __builtin_amdgcn_cvt_pkrtz(a, b);
  union { v2hf f; v2h h; } u; u.f = r;
  return u.h;
}

#define NPTS 500000
#define FUSED_GRID ((NPTS + 255) / 256)   // 1954

// LDS-only barrier: LDS ordering without draining vmcnt (weights in flight)
#define BAR_LDS() asm volatile("s_waitcnt lgkmcnt(0)\n\ts_barrier" ::: "memory")

// offsets in halves inside g_w16
#define OFF_FW    0               // f2..f5: L*16384, [o*128+k]
#define OFF_V2Z   65536           // [j*64+k]
#define OFF_V3Z   69632
#define OFF_V2ZT  73728           // [k*64+j]
#define OFF_V3ZT  77824
#define OFF_VL1T  81920           // [c*64+j]
#define OFF_V2XT  82048
#define OFF_V3XT  82176
#define OFF_VFZ   82304           // [64]
#define OFF_FFW   82368           // [c*128+k]
#define OFF_F1W   82624           // [oc*2+c]
#define OFF_F1P   82880           // f1 padded [o*32+k], k<2 valid else 0
#define W16_DATA  86976
#define W16_TOTAL (W16_DATA + 2048)   // zero pad: junk A-rows stay in-bounds

__device__ __align__(16) _Float16 g_w16[W16_TOTAL];

__device__ __forceinline__ float srelu(float x){
  float c = fminf(fmaxf(x, 0.f), 1.f);
  return c * fmaf(-0.5f, c, x);
}
__device__ __forceinline__ float sreluD(float x){
  return fminf(fmaxf(x, 0.f), 1.f);
}
__device__ __forceinline__ float sreluD_from_z(float z){
  return fminf(sqrtf(2.f * z), 1.f);
}

// ---- packed f16 activations (2 f32 in -> 2 f16 out) ----
__device__ __forceinline__ v2h lrelu_pk(float a, float b){
  v2h x = cvt_pk(a, b);
  v2h m = x * (v2h){(_Float16)0.01f, (_Float16)0.01f};
  return __builtin_elementwise_max(x, m);
}
__device__ __forceinline__ v2h srelu_pk(float a, float b){
  v2h x = cvt_pk(a, b);
  const v2h z0 = (v2h){(_Float16)0.f, (_Float16)0.f};
  const v2h o1 = (v2h){(_Float16)1.f, (_Float16)1.f};
  const v2h hf = (v2h){(_Float16)0.5f, (_Float16)0.5f};
  v2h c = __builtin_elementwise_min(__builtin_elementwise_max(x, z0), o1);
  v2h t = x - c * hf;
  return c * t;
}

// ---------------- prep: fp32 weights -> f16 layouts (+zero pad) ----------------
__global__ __launch_bounds__(256) void prep_kernel(
  const float* __restrict__ f2w, const float* __restrict__ f3w,
  const float* __restrict__ f4w, const float* __restrict__ f5w,
  const float* __restrict__ V2z, const float* __restrict__ V3z,
  const float* __restrict__ Vl1, const float* __restrict__ V2x,
  const float* __restrict__ V3x, const float* __restrict__ Vfz,
  const float* __restrict__ ffw, const float* __restrict__ f1w)
{
  const int i = blockIdx.x * 256 + threadIdx.x;
  if (i >= W16_TOTAL) return;
  if (i >= W16_DATA){ g_w16[i] = (_Float16)0.f; return; }
  float v;
  if (i < 65536){
    const float* W[4] = {f2w, f3w, f4w, f5w};
    v = W[i >> 14][i & 16383];
  } else if (i < 69632)  v = V2z[i - 65536];
  else if (i < 73728)    v = V3z[i - 69632];
  else if (i < 77824){ int r = i - 73728; v = V2z[(r & 63)*64 + (r >> 6)]; }
  else if (i < 81920){ int r = i - 77824; v = V3z[(r & 63)*64 + (r >> 6)]; }
  else if (i < 82048){ int r = i - 81920; v = Vl1[(r & 63)*2 + (r >> 6)]; }
  else if (i < 82176){ int r = i - 82048; v = V2x[(r & 63)*2 + (r >> 6)]; }
  else if (i < 82304){ int r = i - 82176; v = V3x[(r & 63)*2 + (r >> 6)]; }
  else if (i < 82368)    v = Vfz[i - 82304];
  else if (i < 82624)    v = ffw[i - 82368];
  else if (i < 82880)    v = f1w[i - 82624];
  else { int r = i - 82880; int k = r & 31; v = (k < 2) ? f1w[(r >> 5)*2 + k] : 0.f; }
  g_w16[i] = (_Float16)v;
}

// ================= fhat layer: 512 thr, 256 rows =================
// Wave w computes output features [w*16, w*16+16) for ALL 256 rows.
// One A-fragment per kt feeds 16 MFMAs (16 row-tiles).
__device__ __forceinline__ void fh_layer(_Float16* H,
    const _Float16* __restrict__ Wl, const float* __restrict__ Bp,
    int w, int lm, int q)
{
  const v4f bv = *(const v4f*)(Bp + w*16 + q*4);
  v4f acc[16];
#pragma unroll
  for (int nt = 0; nt < 16; ++nt) acc[nt] = bv;

#pragma unroll
  for (int kt = 0; kt < 4; ++kt){
    const int sw = ((kt*4 + q) ^ lm) << 3;
    v8h A = *(const v8h*)(Wl + (w*16 + lm)*128 + kt*32 + q*8);
#pragma unroll
    for (int nt = 0; nt < 16; ++nt){
      v8h B = *(const v8h*)(H + (nt*16 + lm)*128 + sw);
      acc[nt] = __builtin_amdgcn_mfma_f32_16x16x32_f16(A, B, acc[nt], 0,0,0);
    }
  }
  BAR_LDS();
  const int o0 = w*16 + q*4;
  const int coff = (((o0 >> 3) ^ lm) << 3) + (o0 & 7);
#pragma unroll
  for (int nt = 0; nt < 16; ++nt){
    v4h hv;
    *(v2h*)&hv       = lrelu_pk(acc[nt][0], acc[nt][1]);
    *((v2h*)&hv + 1) = lrelu_pk(acc[nt][2], acc[nt][3]);
    *(v4h*)(H + (nt*16 + lm)*128 + coff) = hv;
  }
  BAR_LDS();
}

// ================= vnet pieces (R21/R18 ILP-2 form, barrier-free) =================
__device__ __forceinline__ void vfwd2_l2(_Float16* zoutA, _Float16* zoutB,
    const _Float16* __restrict__ Wz,   // V2Z [o][k]
    const _Float16* __restrict__ WxT,  // V2XT [2][64]
    const _Float16* __restrict__ Wl1T, // VL1T [2][64]
    float dA0, float dA1, float dB0, float dB1, int lm, int q)
{
  v4f accA[4], accB[4];
#pragma unroll
  for (int mt = 0; mt < 4; ++mt){
    accA[mt] = (v4f){0.f,0.f,0.f,0.f};
    accB[mt] = (v4f){0.f,0.f,0.f,0.f};
  }
  const int rs = lm & 7;
#pragma unroll
  for (int kt = 0; kt < 2; ++kt){
    v8h w0 = *(const v8h*)(Wl1T + kt*32 + q*8);
    v8h w1 = *(const v8h*)(Wl1T + 64 + kt*32 + q*8);
    v8h BA, BB;
#pragma unroll
    for (int j2 = 0; j2 < 4; ++j2){
      const float a0 = (float)w0[2*j2  ], a1 = (float)w0[2*j2+1];
      const float c0 = (float)w1[2*j2  ], c1 = (float)w1[2*j2+1];
      ((v2h*)&BA)[j2] = srelu_pk(fmaf(dA0,a0,dA1*c0), fmaf(dA0,a1,dA1*c1));
      ((v2h*)&BB)[j2] = srelu_pk(fmaf(dB0,a0,dB1*c0), fmaf(dB0,a1,dB1*c1));
    }
#pragma unroll
    for (int mt = 0; mt < 4; ++mt){
      v8h A = *(const v8h*)(Wz + (mt*16 + lm)*64 + kt*32 + q*8);
      accA[mt] = __builtin_amdgcn_mfma_f32_16x16x32_f16(A, BA, accA[mt], 0,0,0);
      accB[mt] = __builtin_amdgcn_mfma_f32_16x16x32_f16(A, BB, accB[mt], 0,0,0);
    }
  }
#pragma unroll
  for (int mt = 0; mt < 4; ++mt){
    const int o0 = mt*16 + q*4;
    const int off = (((o0 >> 3) ^ rs) << 3) + (o0 & 7);
    float vA[4], vB[4];
#pragma unroll
    for (int reg = 0; reg < 4; ++reg){
      const float wx0 = (float)WxT[o0 + reg];
      const float wx1 = (float)WxT[64 + o0 + reg];
      vA[reg] = accA[mt][reg] + wx0*dA0 + wx1*dA1;
      vB[reg] = accB[mt][reg] + wx0*dB0 + wx1*dB1;
    }
    v4h hA, hB;
    *(v2h*)&hA       = srelu_pk(vA[0], vA[1]);
    *((v2h*)&hA + 1) = srelu_pk(vA[2], vA[3]);
    *(v2h*)&hB       = srelu_pk(vB[0], vB[1]);
    *((v2h*)&hB + 1) = srelu_pk(vB[2], vB[3]);
    *(v4h*)(zoutA + lm*64 + off) = hA;
    *(v4h*)(zoutB + lm*64 + off) = hB;
  }
}

__device__ __forceinline__ void vfwd2(const _Float16* zinA, _Float16* zoutA,
    const _Float16* zinB, _Float16* zoutB,
    const _Float16* __restrict__ Wz, const _Float16* __restrict__ WxT,
    float dA0, float dA1, float dB0, float dB1, int lm, int q)
{
  v4f accA[4], accB[4];
#pragma unroll
  for (int mt = 0; mt < 4; ++mt){
    accA[mt] = (v4f){0.f,0.f,0.f,0.f};
    accB[mt] = (v4f){0.f,0.f,0.f,0.f};
  }
  const int rs = lm & 7;
#pragma unroll
  for (int kt = 0; kt < 2; ++kt){
    const int sw = (((kt*4 + q) ^ rs) << 3);
    v8h BA = *(const v8h*)(zinA + lm*64 + sw);
    v8h BB = *(const v8h*)(zinB + lm*64 + sw);
#pragma unroll
    for (int mt = 0; mt < 4; ++mt){
      v8h A = *(const v8h*)(Wz + (mt*16 + lm)*64 + kt*32 + q*8);
      accA[mt] = __builtin_amdgcn_mfma_f32_16x16x32_f16(A, BA, accA[mt], 0,0,0);
      accB[mt] = __builtin_amdgcn_mfma_f32_16x16x32_f16(A, BB, accB[mt], 0,0,0);
    }
  }
#pragma unroll
  for (int mt = 0; mt < 4; ++mt){
    const int o0 = mt*16 + q*4;
    const int off = (((o0 >> 3) ^ rs) << 3) + (o0 & 7);
    float vA[4], vB[4];
#pragma unroll
    for (int reg = 0; reg < 4; ++reg){
      const float wx0 = (float)WxT[o0 + reg];
      const float wx1 = (float)WxT[64 + o0 + reg];
      vA[reg] = accA[mt][reg] + wx0*dA0 + wx1*dA1;
      vB[reg] = accB[mt][reg] + wx0*dB0 + wx1*dB1;
    }
    v4h hA, hB;
    *(v2h*)&hA       = srelu_pk(vA[0], vA[1]);
    *((v2h*)&hA + 1) = srelu_pk(vA[2], vA[3]);
    *(v2h*)&hB       = srelu_pk(vB[0], vB[1]);
    *((v2h*)&hB + 1) = srelu_pk(vB[2], vB[3]);
    *(v4h*)(zoutA + lm*64 + off) = hA;
    *(v4h*)(zoutB + lm*64 + off) = hB;
  }
}

__device__ __forceinline__ void vbwd2(const _Float16* ginA, _Float16* zioA,
    const _Float16* ginB, _Float16* zioB,
    const _Float16* __restrict__ WT, int lm, int q)
{
  v4f accA[4], accB[4];
#pragma unroll
  for (int mt = 0; mt < 4; ++mt){
    accA[mt] = (v4f){0.f,0.f,0.f,0.f};
    accB[mt] = (v4f){0.f,0.f,0.f,0.f};
  }
  const int rs = lm & 7;
#pragma unroll
  for (int kt = 0; kt < 2; ++kt){
    const int sw = (((kt*4 + q) ^ rs) << 3);
    v8h BA = *(const v8h*)(ginA + lm*64 + sw);
    v8h BB = *(const v8h*)(ginB + lm*64 + sw);
#pragma unroll
    for (int mt = 0; mt < 4; ++mt){
      v8h A = *(const v8h*)(WT + (mt*16 + lm)*64 + kt*32 + q*8);
      accA[mt] = __builtin_amdgcn_mfma_f32_16x16x32_f16(A, BA, accA[mt], 0,0,0);
      accB[mt] = __builtin_amdgcn_mfma_f32_16x16x32_f16(A, BB, accB[mt], 0,0,0);
    }
  }
#pragma unroll
  for (int mt = 0; mt < 4; ++mt){
    const int k0 = mt*16 + q*4;
    const int off = (((k0 >> 3) ^ rs) << 3) + (k0 & 7);
    _Float16* pA = zioA + lm*64 + off;
    _Float16* pB = zioB + lm*64 + off;
    v4h zA = *(const v4h*)pA;
    v4h zB = *(const v4h*)pB;
    float sA0 = accA[mt][0] * sreluD_from_z((float)zA[0]);
    float sA1 = accA[mt][1] * sreluD_from_z((float)zA[1]);
    float sA2 = accA[mt][2] * sreluD_from_z((float)zA[2]);
    float sA3 = accA[mt][3] * sreluD_from_z((float)zA[3]);
    float sB0 = accB[mt][0] * sreluD_from_z((float)zB[0]);
    float sB1 = accB[mt][1] * sreluD_from_z((float)zB[1]);
    float sB2 = accB[mt][2] * sreluD_from_z((float)zB[2]);
    float sB3 = accB[mt][3] * sreluD_from_z((float)zB[3]);
    v4h gA, gB;
    *(v2h*)&gA       = cvt_pk(sA0, sA1);
    *((v2h*)&gA + 1) = cvt_pk(sA2, sA3);
    *(v2h*)&gB       = cvt_pk(sB0, sB1);
    *((v2h*)&gB + 1) = cvt_pk(sB2, sB3);
    *(v4h*)pA = gA;
    *(v4h*)pB = gB;
  }
}

__device__ __forceinline__ void vbwd2_l1(_Float16* zioA, _Float16* zioB,
    const _Float16* __restrict__ WT,   // V2ZT
    const _Float16* __restrict__ Wl1T, // VL1T [2][64]
    float dA0, float dA1, float dB0, float dB1, int lm, int q)
{
  v4f accA[4], accB[4];
#pragma unroll
  for (int mt = 0; mt < 4; ++mt){
    accA[mt] = (v4f){0.f,0.f,0.f,0.f};
    accB[mt] = (v4f){0.f,0.f,0.f,0.f};
  }
  const int rs = lm & 7;
#pragma unroll
  for (int kt = 0; kt < 2; ++kt){
    const int sw = (((kt*4 + q) ^ rs) << 3);
    v8h BA = *(const v8h*)(zioA + lm*64 + sw);
    v8h BB = *(const v8h*)(zioB + lm*64 + sw);
#pragma unroll
    for (int mt = 0; mt < 4; ++mt){
      v8h A = *(const v8h*)(WT + (mt*16 + lm)*64 + kt*32 + q*8);
      accA[mt] = __builtin_amdgcn_mfma_f32_16x16x32_f16(A, BA, accA[mt], 0,0,0);
      accB[mt] = __builtin_amdgcn_mfma_f32_16x16x32_f16(A, BB, accB[mt], 0,0,0);
    }
  }
#pragma unroll
  for (int mt = 0; mt < 4; ++mt){
    const int k0 = mt*16 + q*4;
    const int off = (((k0 >> 3) ^ rs) << 3) + (k0 & 7);
    v4h w0 = *(const v4h*)(Wl1T + k0);
    v4h w1 = *(const v4h*)(Wl1T + 64 + k0);
    float sA[4], sB[4];
#pragma unroll
    for (int reg = 0; reg < 4; ++reg){
      const float a1A = fmaf(dA0, (float)w0[reg], dA1 * (float)w1[reg]);
      const float a1B = fmaf(dB0, (float)w0[reg], dB1 * (float)w1[reg]);
      sA[reg] = accA[mt][reg] * sreluD(a1A);
      sB[reg] = accB[mt][reg] * sreluD(a1B);
    }
    v4h gA, gB;
    *(v2h*)&gA       = cvt_pk(sA[0], sA[1]);
    *((v2h*)&gA + 1) = cvt_pk(sA[2], sA[3]);
    *(v2h*)&gB       = cvt_pk(sB[0], sB[1]);
    *((v2h*)&gB + 1) = cvt_pk(sB[2], sB[3]);
    *(v4h*)(zioA + lm*64 + off) = gA;
    *(v4h*)(zioB + lm*64 + off) = gB;
  }
}

__device__ __forceinline__ void gacc2(v4f& aGA, v4f& aGB,
    const _Float16* __restrict__ WxTbase,
    const _Float16* ZA, const _Float16* ZB, int lm, int q)
{
  const int rs = lm & 7;
#pragma unroll
  for (int kt = 0; kt < 2; ++kt){
    const int sw = (((kt*4 + q) ^ rs) << 3);
    v8h A  = *(const v8h*)(WxTbase + lm*64 + kt*32 + q*8);
    v8h BA = *(const v8h*)(ZA + lm*64 + sw);
    v8h BB = *(const v8h*)(ZB + lm*64 + sw);
    aGA = __builtin_amdgcn_mfma_f32_16x16x32_f16(A, BA, aGA, 0,0,0);
    aGB = __builtin_amdgcn_mfma_f32_16x16x32_f16(A, BB, aGB, 0,0,0);
  }
}

// ================= merged kernel: fhat -> ff(regs) -> vnet -> combine =================
__global__ __launch_bounds__(512, 4) void fused_kernel(
  const float* __restrict__ X, const float* __restrict__ Xst,
  const float* __restrict__ Vfx,
  const float* __restrict__ f1b, const float* __restrict__ f2b,
  const float* __restrict__ f3b, const float* __restrict__ f4b,
  const float* __restrict__ f5b, const float* __restrict__ ffb,
  float* __restrict__ out)
{
  __shared__ __align__(16) char smem[65536];   // fhat H 256x128 | vnet 8x8KB/wave
  _Float16* const H = (_Float16*)smem;

  const int b  = blockIdx.x;
  const int t  = threadIdx.x;
  const int w  = t >> 6;     // 0..7
  const int l  = t & 63;
  const int lm = l & 15;
  const int q  = l >> 4;
  const int rs = lm & 7;
  const int row0 = b*256 + w*32;

  const int r0 = row0 + lm;
  const int r1 = row0 + 16 + lm;
  const int rc0 = r0 < NPTS ? r0 : NPTS-1;
  const int rc1 = r1 < NPTS ? r1 : NPTS-1;
  const float2 x0 = *(const float2*)(X + rc0*2);
  const float2 x1 = *(const float2*)(X + rc1*2);

  // ========== fhat phase ==========
  // ---- f1 via MFMA: A = f1w padded to K=32, B = x (q==0 lanes k=0,1) ----
  // Per-wave: writes its own 32 rows (w*32..w*32+31), all 128 feats.
  {
    v8h Bx0 = (v8h){(_Float16)0.f,(_Float16)0.f,(_Float16)0.f,(_Float16)0.f,
                    (_Float16)0.f,(_Float16)0.f,(_Float16)0.f,(_Float16)0.f};
    v8h Bx1 = Bx0;
    if (q == 0){
      Bx0[0] = (_Float16)x0.x; Bx0[1] = (_Float16)x0.y;
      Bx1[0] = (_Float16)x1.x; Bx1[1] = (_Float16)x1.y;
    }
#pragma unroll
    for (int mt = 0; mt < 8; ++mt){
      const int o0 = mt*16 + q*4;
      const v4f bv = *(const v4f*)(f1b + o0);
      v8h A = *(const v8h*)(g_w16 + OFF_F1P + (mt*16 + lm)*32 + q*8);
      v4f a0 = __builtin_amdgcn_mfma_f32_16x16x32_f16(A, Bx0, bv, 0,0,0);
      v4f a1 = __builtin_amdgcn_mfma_f32_16x16x32_f16(A, Bx1, bv, 0,0,0);
      const int coff = (((o0 >> 3) ^ lm) << 3) + (o0 & 7);
      v4h h0, h1;
      *(v2h*)&h0       = lrelu_pk(a0[0], a0[1]);
      *((v2h*)&h0 + 1) = lrelu_pk(a0[2], a0[3]);
      *(v2h*)&h1       = lrelu_pk(a1[0], a1[1]);
      *((v2h*)&h1 + 1) = lrelu_pk(a1[2], a1[3]);
      *(v4h*)(H + (w*32 + lm)*128 + coff)      = h0;
      *(v4h*)(H + (w*32 + 16 + lm)*128 + coff) = h1;
    }
  }
  BAR_LDS();

  fh_layer(H, g_w16 + OFF_FW,         f2b, w, lm, q);
  fh_layer(H, g_w16 + OFF_FW + 16384, f3b, w, lm, q);
  fh_layer(H, g_w16 + OFF_FW + 32768, f4b, w, lm, q);
  fh_layer(H, g_w16 + OFF_FW + 49152, f5b, w, lm, q);

  // ---- ff via MFMA on the wave's OWN rows (w*32..w*32+31) ----
  // Results stay in registers (valid on q==0 lanes).
  float fhA0, fhA1, fhB0, fhB1;
  {
    v4f a0 = (v4f){0.f,0.f,0.f,0.f};
    v4f a1 = (v4f){0.f,0.f,0.f,0.f};
#pragma unroll
    for (int kt = 0; kt < 4; ++kt){
      const int sw = ((kt*4 + q) ^ lm) << 3;
      v8h A  = *(const v8h*)(g_w16 + OFF_FFW + lm*128 + kt*32 + q*8);
      v8h B0 = *(const v8h*)(H + (w*32 + lm)*128 + sw);
      v8h B1 = *(const v8h*)(H + (w*32 + 16 + lm)*128 + sw);
      a0 = __builtin_amdgcn_mfma_f32_16x16x32_f16(A, B0, a0, 0,0,0);
      a1 = __builtin_amdgcn_mfma_f32_16x16x32_f16(A, B1, a1, 0,0,0);
    }
    const float fb0 = ffb[0], fb1 = ffb[1];
    fhA0 = a0[0] + fb0; fhA1 = a0[1] + fb1;
    fhB0 = a1[0] + fb0; fhB1 = a1[1] + fb1;
  }

  // ========== vnet phase (wave-local slice; after f5's trailing barrier
  // only the owning wave touches its own 8KB slice) ==========
  _Float16* const ZA2 = (_Float16*)(smem + w*8192);
  _Float16* const ZA3 = ZA2 + 1024;
  _Float16* const ZB2 = ZA2 + 2048;
  _Float16* const ZB3 = ZA2 + 3072;

  const float2 sA = *(const float2*)(Xst + rc0*2);
  const float2 sB = *(const float2*)(Xst + rc1*2);
  const float dA0 = x0.x - sA.x, dA1 = x0.y - sA.y;
  const float dB0 = x1.x - sB.x, dB1 = x1.y - sB.y;
  const float vfx0 = Vfx[0], vfx1 = Vfx[1];

  // fwd: z2 (z1 in registers), z3
  vfwd2_l2(ZA2, ZB2, g_w16 + OFF_V2Z, g_w16 + OFF_V2XT, g_w16 + OFF_VL1T,
           dA0, dA1, dB0, dB1, lm, q);
  vfwd2(ZA2, ZA3, ZB2, ZB3, g_w16 + OFF_V3Z, g_w16 + OFF_V3XT,
        dA0, dA1, dB0, dB1, lm, q);

  // zf head for both (A row 0 = Vfz)
  float VVrA, sfA, VVrB, sfB;
  {
    v4f aSA = (v4f){0.f,0.f,0.f,0.f};
    v4f aSB = (v4f){0.f,0.f,0.f,0.f};
#pragma unroll
    for (int kt = 0; kt < 2; ++kt){
      const int sw = (((kt*4 + q) ^ rs) << 3);
      v8h A  = *(const v8h*)(g_w16 + OFF_VFZ + lm*64 + kt*32 + q*8);
      v8h BA = *(const v8h*)(ZA3 + lm*64 + sw);
      v8h BB = *(const v8h*)(ZB3 + lm*64 + sw);
      aSA = __builtin_amdgcn_mfma_f32_16x16x32_f16(A, BA, aSA, 0,0,0);
      aSB = __builtin_amdgcn_mfma_f32_16x16x32_f16(A, BB, aSB, 0,0,0);
    }
    const float afA = fmaf(vfx0, dA0, fmaf(vfx1, dA1, aSA[0]));
    const float zfA = srelu(afA);
    VVrA = srelu(zfA) + 0.01f * fmaf(dA0, dA0, dA1*dA1);
    sfA  = sreluD(zfA) * sreluD(afA);
    const float afB = fmaf(vfx0, dB0, fmaf(vfx1, dB1, aSB[0]));
    const float zfB = srelu(afB);
    VVrB = srelu(zfB) + 0.01f * fmaf(dB0, dB0, dB1*dB1);
    sfB  = sreluD(zfB) * sreluD(afB);
  }

  // u3 = Vfz * srelu'(a3) (sf deferred; in place over Z3)
#pragma unroll
  for (int cc = 0; cc < 2; ++cc){
    const int c = q*2 + cc;
    const int sw = ((c ^ rs) << 3);
    v8h vf = *(const v8h*)(g_w16 + OFF_VFZ + c*8);
    _Float16* pA = ZA3 + lm*64 + sw;
    _Float16* pB = ZB3 + lm*64 + sw;
    v8h zA = *(const v8h*)pA;
    v8h zB = *(const v8h*)pB;
    v8h uA, uB;
#pragma unroll
    for (int j2 = 0; j2 < 4; ++j2){
      float a0 = (float)vf[2*j2  ] * sreluD_from_z((float)zA[2*j2  ]);
      float a1 = (float)vf[2*j2+1] * sreluD_from_z((float)zA[2*j2+1]);
      float b0 = (float)vf[2*j2  ] * sreluD_from_z((float)zB[2*j2  ]);
      float b1 = (float)vf[2*j2+1] * sreluD_from_z((float)zB[2*j2+1]);
      ((v2h*)&uA)[j2] = cvt_pk(a0, a1);
      ((v2h*)&uB)[j2] = cvt_pk(b0, b1);
    }
    *(v8h*)pA = uA;
    *(v8h*)pB = uB;
  }

  // incremental gradV, interleaved with backward (arena reuse)
  v4f aGA = (v4f){0.f,0.f,0.f,0.f};
  v4f aGB = (v4f){0.f,0.f,0.f,0.f};

  gacc2(aGA, aGB, g_w16 + OFF_V3XT, ZA3, ZB3, lm, q);             // L3 (ga3=u3)
  vbwd2(ZA3, ZA2, ZB3, ZB2, g_w16 + OFF_V3ZT, lm, q);             // ga2 -> Z2
  gacc2(aGA, aGB, g_w16 + OFF_V2XT, ZA2, ZB2, lm, q);             // L2
  vbwd2_l1(ZA2, ZB2, g_w16 + OFF_V2ZT, g_w16 + OFF_VL1T,
           dA0, dA1, dB0, dB1, lm, q);                            // ga1 -> Z2
  gacc2(aGA, aGB, g_w16 + OFF_VL1T, ZA2, ZB2, lm, q);             // L1

  const float g0A = fmaf(0.02f, dA0, sfA * (vfx0 + aGA[0]));
  const float g1A = fmaf(0.02f, dA1, sfA * (vfx1 + aGA[1]));
  const float g0B = fmaf(0.02f, dB0, sfB * (vfx0 + aGB[0]));
  const float g1B = fmaf(0.02f, dB1, sfB * (vfx1 + aGB[1]));

  // ========== combine in registers, store out ==========
  if (q == 0){
    if (r0 < NPTS){
      const float Vn  = fmaf(g0A, g0A, g1A*g1A);
      const float num = fmaf(0.1f, VVrA, fmaf(fhA0, g0A, fhA1*g1A));
      const float fm  = fmaxf(num, 0.f) / (Vn + 1e-10f);
      *(float2*)(out + r0*2) =
        make_float2(fmaf(-g0A, fm, fhA0), fmaf(-g1A, fm, fhA1));
    }
    if (r1 < NPTS){
      const float Vn  = fmaf(g0B, g0B, g1B*g1B);
      const float num = fmaf(0.1f, VVrB, fmaf(fhB0, g0B, fhB1*g1B));
      const float fm  = fmaxf(num, 0.f) / (Vn + 1e-10f);
      *(float2*)(out + r1*2) =
        make_float2(fmaf(-g0B, fm, fhB0), fmaf(-g1B, fm, fhB1));
    }
  }
}

extern "C" void kernel_launch(void* const* d_in, const int* in_sizes, int n_in,
                              void* d_out, int out_size, void* d_ws, size_t ws_size,
                              hipStream_t stream)
{
  (void)d_ws; (void)ws_size; (void)n_in; (void)in_sizes; (void)out_size;
  const float* X   = (const float*)d_in[0];
  const float* Xst = (const float*)d_in[1];
  const float* Vl1 = (const float*)d_in[2];
  const float* V2x = (const float*)d_in[3];
  const float* V2z = (const float*)d_in[4];
  const float* V3x = (const float*)d_in[5];
  const float* V3z = (const float*)d_in[6];
  const float* Vfx = (const float*)d_in[7];
  const float* Vfz = (const float*)d_in[8];
  const float* f1w = (const float*)d_in[9];
  const float* f1b = (const float*)d_in[10];
  const float* f2w = (const float*)d_in[11];
  const float* f2b = (const float*)d_in[12];
  const float* f3w = (const float*)d_in[13];
  const float* f3b = (const float*)d_in[14];
  const float* f4w = (const float*)d_in[15];
  const float* f4b = (const float*)d_in[16];
  const float* f5w = (const float*)d_in[17];
  const float* f5b = (const float*)d_in[18];
  const float* ffw = (const float*)d_in[19];
  const float* ffb = (const float*)d_in[20];

  prep_kernel<<<(W16_TOTAL + 255)/256, 256, 0, stream>>>(
      f2w, f3w, f4w, f5w, V2z, V3z, Vl1, V2x, V3x, Vfz, ffw, f1w);
  fused_kernel<<<FUSED_GRID, 512, 0, stream>>>(
      X, Xst, Vfx, f1b, f2b, f3b, f4b, f5b, ffb, (float*)d_out);
}

// Round 6
// 254.291 us; speedup vs baseline: 2.4519x; 1.0075x over previous
//
#include <hip/hip_runtime.h>

// ICNN_net_1503238553972 — round 24: VALU cuts in vnet (R23 frame kept).
// R23 (256-row/512-thr, 188us fused) left VALU as the top busy pipe (45%).
// Two targeted cuts, both register-exact re-expressions:
//  (1) Wx@d folded into MFMA: extra K-block with A = padded WxP[64][32]
//      (k<2 valid), B = d in q==0 lanes (same pattern as the f1 MFMA).
//      Removes 64 scalar f16 global loads + 128 v_fma per wave.
//  (2) srelu'(a2) carried in registers from vfwd2_l2's epilogue to vbwd2
//      (same (mt,reg,lm,q) coordinates): clamp(a2,0,1) == min(sqrt(2z),1).
//      Removes 32 v_sqrt + 32 cvt + 8 ds_read_b64 per wave.
// Everything else byte-identical to R23. launch_bounds(512,4), grid 1954.

typedef _Float16 v2h __attribute__((ext_vector_type(2)));
typedef __fp16   v2hf __attribute__((ext_vector_type(2)));
typedef _Float16 v4h __attribute__((ext_vector_type(4)));
typedef _Float16 v8h __attribute__((ext_vector_type(8)));
typedef float    v4f __attribute__((ext_vector_type(4)));

__device__ __forceinline__ v2h cvt_pk(float a, float b){
  v2hf r = __builtin_amdgcn_cvt_pkrtz(a, b);
  union { v2hf f; v2h h; } u; u.f = r;
  return u.h;
}

#define NPTS 500000
#define FUSED_GRID ((NPTS + 255) / 256)   // 1954

// LDS-only barrier: LDS ordering without draining vmcnt (weights in flight)
#define BAR_LDS() asm volatile("s_waitcnt lgkmcnt(0)\n\ts_barrier" ::: "memory")

// offsets in halves inside g_w16
#define OFF_FW    0               // f2..f5: L*16384, [o*128+k]
#define OFF_V2Z   65536           // [j*64+k]
#define OFF_V3Z   69632
#define OFF_V2ZT  73728           // [k*64+j]
#define OFF_V3ZT  77824
#define OFF_VL1T  81920           // [c*64+j]
#define OFF_V2XT  82048
#define OFF_V3XT  82176
#define OFF_VFZ   82304           // [64]
#define OFF_FFW   82368           // [c*128+k]
#define OFF_F1W   82624           // [oc*2+c]
#define OFF_F1P   82880           // f1 padded [o*32+k], k<2 valid else 0
#define OFF_V2XP  86976           // V2x padded [o*32+k], k<2 valid else 0
#define OFF_V3XP  89024           // V3x padded [o*32+k], k<2 valid else 0
#define W16_DATA  91072
#define W16_TOTAL (W16_DATA + 2048)   // zero pad: junk A-rows stay in-bounds

__device__ __align__(16) _Float16 g_w16[W16_TOTAL];

__device__ __forceinline__ float srelu(float x){
  float c = fminf(fmaxf(x, 0.f), 1.f);
  return c * fmaf(-0.5f, c, x);
}
__device__ __forceinline__ float sreluD(float x){
  return fminf(fmaxf(x, 0.f), 1.f);
}
__device__ __forceinline__ float sreluD_from_z(float z){
  return fminf(sqrtf(2.f * z), 1.f);
}

// ---- packed f16 activations (2 f32 in -> 2 f16 out) ----
__device__ __forceinline__ v2h lrelu_pk(float a, float b){
  v2h x = cvt_pk(a, b);
  v2h m = x * (v2h){(_Float16)0.01f, (_Float16)0.01f};
  return __builtin_elementwise_max(x, m);
}
__device__ __forceinline__ v2h srelu_pk(float a, float b){
  v2h x = cvt_pk(a, b);
  const v2h z0 = (v2h){(_Float16)0.f, (_Float16)0.f};
  const v2h o1 = (v2h){(_Float16)1.f, (_Float16)1.f};
  const v2h hf = (v2h){(_Float16)0.5f, (_Float16)0.5f};
  v2h c = __builtin_elementwise_min(__builtin_elementwise_max(x, z0), o1);
  v2h t = x - c * hf;
  return c * t;
}

// ---------------- prep: fp32 weights -> f16 layouts (+zero pad) ----------------
__global__ __launch_bounds__(256) void prep_kernel(
  const float* __restrict__ f2w, const float* __restrict__ f3w,
  const float* __restrict__ f4w, const float* __restrict__ f5w,
  const float* __restrict__ V2z, const float* __restrict__ V3z,
  const float* __restrict__ Vl1, const float* __restrict__ V2x,
  const float* __restrict__ V3x, const float* __restrict__ Vfz,
  const float* __restrict__ ffw, const float* __restrict__ f1w)
{
  const int i = blockIdx.x * 256 + threadIdx.x;
  if (i >= W16_TOTAL) return;
  if (i >= W16_DATA){ g_w16[i] = (_Float16)0.f; return; }
  float v;
  if (i < 65536){
    const float* W[4] = {f2w, f3w, f4w, f5w};
    v = W[i >> 14][i & 16383];
  } else if (i < 69632)  v = V2z[i - 65536];
  else if (i < 73728)    v = V3z[i - 69632];
  else if (i < 77824){ int r = i - 73728; v = V2z[(r & 63)*64 + (r >> 6)]; }
  else if (i < 81920){ int r = i - 77824; v = V3z[(r & 63)*64 + (r >> 6)]; }
  else if (i < 82048){ int r = i - 81920; v = Vl1[(r & 63)*2 + (r >> 6)]; }
  else if (i < 82176){ int r = i - 82048; v = V2x[(r & 63)*2 + (r >> 6)]; }
  else if (i < 82304){ int r = i - 82176; v = V3x[(r & 63)*2 + (r >> 6)]; }
  else if (i < 82368)    v = Vfz[i - 82304];
  else if (i < 82624)    v = ffw[i - 82368];
  else if (i < 82880)    v = f1w[i - 82624];
  else if (i < 86976){ int r = i - 82880; int k = r & 31; v = (k < 2) ? f1w[(r >> 5)*2 + k] : 0.f; }
  else if (i < 89024){ int r = i - 86976; int k = r & 31; v = (k < 2) ? V2x[(r >> 5)*2 + k] : 0.f; }
  else               { int r = i - 89024; int k = r & 31; v = (k < 2) ? V3x[(r >> 5)*2 + k] : 0.f; }
  g_w16[i] = (_Float16)v;
}

// ================= fhat layer: 512 thr, 256 rows (R23 form) =================
__device__ __forceinline__ void fh_layer(_Float16* H,
    const _Float16* __restrict__ Wl, const float* __restrict__ Bp,
    int w, int lm, int q)
{
  const v4f bv = *(const v4f*)(Bp + w*16 + q*4);
  v4f acc[16];
#pragma unroll
  for (int nt = 0; nt < 16; ++nt) acc[nt] = bv;

#pragma unroll
  for (int kt = 0; kt < 4; ++kt){
    const int sw = ((kt*4 + q) ^ lm) << 3;
    v8h A = *(const v8h*)(Wl + (w*16 + lm)*128 + kt*32 + q*8);
#pragma unroll
    for (int nt = 0; nt < 16; ++nt){
      v8h B = *(const v8h*)(H + (nt*16 + lm)*128 + sw);
      acc[nt] = __builtin_amdgcn_mfma_f32_16x16x32_f16(A, B, acc[nt], 0,0,0);
    }
  }
  BAR_LDS();
  const int o0 = w*16 + q*4;
  const int coff = (((o0 >> 3) ^ lm) << 3) + (o0 & 7);
#pragma unroll
  for (int nt = 0; nt < 16; ++nt){
    v4h hv;
    *(v2h*)&hv       = lrelu_pk(acc[nt][0], acc[nt][1]);
    *((v2h*)&hv + 1) = lrelu_pk(acc[nt][2], acc[nt][3]);
    *(v4h*)(H + (nt*16 + lm)*128 + coff) = hv;
  }
  BAR_LDS();
}

// ================= vnet pieces (ILP-2; Wx@d folded into MFMA) =================
// layer-2 fwd: z1 B-frags in registers; d-term as extra MFMA K-block;
// srelu'(a2) carried out in registers (sdA/sdB, indexed mt*4+reg).
__device__ __forceinline__ void vfwd2_l2(_Float16* zoutA, _Float16* zoutB,
    const _Float16* __restrict__ Wz,   // V2Z [o][k]
    const _Float16* __restrict__ WxP,  // V2XP [o][32], k<2 valid
    const _Float16* __restrict__ Wl1T, // VL1T [2][64]
    v8h BdA, v8h BdB,
    float dA0, float dA1, float dB0, float dB1,
    float* __restrict__ sdA, float* __restrict__ sdB,
    int lm, int q)
{
  v4f accA[4], accB[4];
#pragma unroll
  for (int mt = 0; mt < 4; ++mt){
    accA[mt] = (v4f){0.f,0.f,0.f,0.f};
    accB[mt] = (v4f){0.f,0.f,0.f,0.f};
  }
  const int rs = lm & 7;
  // d-term: acc += WxP @ Bd
#pragma unroll
  for (int mt = 0; mt < 4; ++mt){
    v8h Ax = *(const v8h*)(WxP + (mt*16 + lm)*32 + q*8);
    accA[mt] = __builtin_amdgcn_mfma_f32_16x16x32_f16(Ax, BdA, accA[mt], 0,0,0);
    accB[mt] = __builtin_amdgcn_mfma_f32_16x16x32_f16(Ax, BdB, accB[mt], 0,0,0);
  }
#pragma unroll
  for (int kt = 0; kt < 2; ++kt){
    v8h w0 = *(const v8h*)(Wl1T + kt*32 + q*8);
    v8h w1 = *(const v8h*)(Wl1T + 64 + kt*32 + q*8);
    v8h BA, BB;
#pragma unroll
    for (int j2 = 0; j2 < 4; ++j2){
      const float a0 = (float)w0[2*j2  ], a1 = (float)w0[2*j2+1];
      const float c0 = (float)w1[2*j2  ], c1 = (float)w1[2*j2+1];
      ((v2h*)&BA)[j2] = srelu_pk(fmaf(dA0,a0,dA1*c0), fmaf(dA0,a1,dA1*c1));
      ((v2h*)&BB)[j2] = srelu_pk(fmaf(dB0,a0,dB1*c0), fmaf(dB0,a1,dB1*c1));
    }
#pragma unroll
    for (int mt = 0; mt < 4; ++mt){
      v8h A = *(const v8h*)(Wz + (mt*16 + lm)*64 + kt*32 + q*8);
      accA[mt] = __builtin_amdgcn_mfma_f32_16x16x32_f16(A, BA, accA[mt], 0,0,0);
      accB[mt] = __builtin_amdgcn_mfma_f32_16x16x32_f16(A, BB, accB[mt], 0,0,0);
    }
  }
#pragma unroll
  for (int mt = 0; mt < 4; ++mt){
    const int o0 = mt*16 + q*4;
    const int off = (((o0 >> 3) ^ rs) << 3) + (o0 & 7);
#pragma unroll
    for (int reg = 0; reg < 4; ++reg){
      sdA[mt*4 + reg] = sreluD(accA[mt][reg]);
      sdB[mt*4 + reg] = sreluD(accB[mt][reg]);
    }
    v4h hA, hB;
    *(v2h*)&hA       = srelu_pk(accA[mt][0], accA[mt][1]);
    *((v2h*)&hA + 1) = srelu_pk(accA[mt][2], accA[mt][3]);
    *(v2h*)&hB       = srelu_pk(accB[mt][0], accB[mt][1]);
    *((v2h*)&hB + 1) = srelu_pk(accB[mt][2], accB[mt][3]);
    *(v4h*)(zoutA + lm*64 + off) = hA;
    *(v4h*)(zoutB + lm*64 + off) = hB;
  }
}

// layer-3 fwd (B from LDS); d-term as extra MFMA K-block
__device__ __forceinline__ void vfwd2(const _Float16* zinA, _Float16* zoutA,
    const _Float16* zinB, _Float16* zoutB,
    const _Float16* __restrict__ Wz,   // V3Z
    const _Float16* __restrict__ WxP,  // V3XP [o][32]
    v8h BdA, v8h BdB, int lm, int q)
{
  v4f accA[4], accB[4];
#pragma unroll
  for (int mt = 0; mt < 4; ++mt){
    accA[mt] = (v4f){0.f,0.f,0.f,0.f};
    accB[mt] = (v4f){0.f,0.f,0.f,0.f};
  }
  const int rs = lm & 7;
#pragma unroll
  for (int mt = 0; mt < 4; ++mt){
    v8h Ax = *(const v8h*)(WxP + (mt*16 + lm)*32 + q*8);
    accA[mt] = __builtin_amdgcn_mfma_f32_16x16x32_f16(Ax, BdA, accA[mt], 0,0,0);
    accB[mt] = __builtin_amdgcn_mfma_f32_16x16x32_f16(Ax, BdB, accB[mt], 0,0,0);
  }
#pragma unroll
  for (int kt = 0; kt < 2; ++kt){
    const int sw = (((kt*4 + q) ^ rs) << 3);
    v8h BA = *(const v8h*)(zinA + lm*64 + sw);
    v8h BB = *(const v8h*)(zinB + lm*64 + sw);
#pragma unroll
    for (int mt = 0; mt < 4; ++mt){
      v8h A = *(const v8h*)(Wz + (mt*16 + lm)*64 + kt*32 + q*8);
      accA[mt] = __builtin_amdgcn_mfma_f32_16x16x32_f16(A, BA, accA[mt], 0,0,0);
      accB[mt] = __builtin_amdgcn_mfma_f32_16x16x32_f16(A, BB, accB[mt], 0,0,0);
    }
  }
#pragma unroll
  for (int mt = 0; mt < 4; ++mt){
    const int o0 = mt*16 + q*4;
    const int off = (((o0 >> 3) ^ rs) << 3) + (o0 & 7);
    v4h hA, hB;
    *(v2h*)&hA       = srelu_pk(accA[mt][0], accA[mt][1]);
    *((v2h*)&hA + 1) = srelu_pk(accA[mt][2], accA[mt][3]);
    *(v2h*)&hB       = srelu_pk(accB[mt][0], accB[mt][1]);
    *((v2h*)&hB + 1) = srelu_pk(accB[mt][2], accB[mt][3]);
    *(v4h*)(zoutA + lm*64 + off) = hA;
    *(v4h*)(zoutB + lm*64 + off) = hB;
  }
}

// backward layer-3->2: srelu'(a2) from carried registers (no z read, no sqrt)
__device__ __forceinline__ void vbwd2(const _Float16* ginA, _Float16* zioA,
    const _Float16* ginB, _Float16* zioB,
    const _Float16* __restrict__ WT,
    const float* __restrict__ sdA, const float* __restrict__ sdB,
    int lm, int q)
{
  v4f accA[4], accB[4];
#pragma unroll
  for (int mt = 0; mt < 4; ++mt){
    accA[mt] = (v4f){0.f,0.f,0.f,0.f};
    accB[mt] = (v4f){0.f,0.f,0.f,0.f};
  }
  const int rs = lm & 7;
#pragma unroll
  for (int kt = 0; kt < 2; ++kt){
    const int sw = (((kt*4 + q) ^ rs) << 3);
    v8h BA = *(const v8h*)(ginA + lm*64 + sw);
    v8h BB = *(const v8h*)(ginB + lm*64 + sw);
#pragma unroll
    for (int mt = 0; mt < 4; ++mt){
      v8h A = *(const v8h*)(WT + (mt*16 + lm)*64 + kt*32 + q*8);
      accA[mt] = __builtin_amdgcn_mfma_f32_16x16x32_f16(A, BA, accA[mt], 0,0,0);
      accB[mt] = __builtin_amdgcn_mfma_f32_16x16x32_f16(A, BB, accB[mt], 0,0,0);
    }
  }
#pragma unroll
  for (int mt = 0; mt < 4; ++mt){
    const int k0 = mt*16 + q*4;
    const int off = (((k0 >> 3) ^ rs) << 3) + (k0 & 7);
    v4h gA, gB;
    *(v2h*)&gA       = cvt_pk(accA[mt][0]*sdA[mt*4+0], accA[mt][1]*sdA[mt*4+1]);
    *((v2h*)&gA + 1) = cvt_pk(accA[mt][2]*sdA[mt*4+2], accA[mt][3]*sdA[mt*4+3]);
    *(v2h*)&gB       = cvt_pk(accB[mt][0]*sdB[mt*4+0], accB[mt][1]*sdB[mt*4+1]);
    *((v2h*)&gB + 1) = cvt_pk(accB[mt][2]*sdB[mt*4+2], accB[mt][3]*sdB[mt*4+3]);
    *(v4h*)(zioA + lm*64 + off) = gA;
    *(v4h*)(zioB + lm*64 + off) = gB;
  }
}

__device__ __forceinline__ void vbwd2_l1(_Float16* zioA, _Float16* zioB,
    const _Float16* __restrict__ WT,   // V2ZT
    const _Float16* __restrict__ Wl1T, // VL1T [2][64]
    float dA0, float dA1, float dB0, float dB1, int lm, int q)
{
  v4f accA[4], accB[4];
#pragma unroll
  for (int mt = 0; mt < 4; ++mt){
    accA[mt] = (v4f){0.f,0.f,0.f,0.f};
    accB[mt] = (v4f){0.f,0.f,0.f,0.f};
  }
  const int rs = lm & 7;
#pragma unroll
  for (int kt = 0; kt < 2; ++kt){
    const int sw = (((kt*4 + q) ^ rs) << 3);
    v8h BA = *(const v8h*)(zioA + lm*64 + sw);
    v8h BB = *(const v8h*)(zioB + lm*64 + sw);
#pragma unroll
    for (int mt = 0; mt < 4; ++mt){
      v8h A = *(const v8h*)(WT + (mt*16 + lm)*64 + kt*32 + q*8);
      accA[mt] = __builtin_amdgcn_mfma_f32_16x16x32_f16(A, BA, accA[mt], 0,0,0);
      accB[mt] = __builtin_amdgcn_mfma_f32_16x16x32_f16(A, BB, accB[mt], 0,0,0);
    }
  }
#pragma unroll
  for (int mt = 0; mt < 4; ++mt){
    const int k0 = mt*16 + q*4;
    const int off = (((k0 >> 3) ^ rs) << 3) + (k0 & 7);
    v4h w0 = *(const v4h*)(Wl1T + k0);
    v4h w1 = *(const v4h*)(Wl1T + 64 + k0);
    float sA[4], sB[4];
#pragma unroll
    for (int reg = 0; reg < 4; ++reg){
      const float a1A = fmaf(dA0, (float)w0[reg], dA1 * (float)w1[reg]);
      const float a1B = fmaf(dB0, (float)w0[reg], dB1 * (float)w1[reg]);
      sA[reg] = accA[mt][reg] * sreluD(a1A);
      sB[reg] = accB[mt][reg] * sreluD(a1B);
    }
    v4h gA, gB;
    *(v2h*)&gA       = cvt_pk(sA[0], sA[1]);
    *((v2h*)&gA + 1) = cvt_pk(sA[2], sA[3]);
    *(v2h*)&gB       = cvt_pk(sB[0], sB[1]);
    *((v2h*)&gB + 1) = cvt_pk(sB[2], sB[3]);
    *(v4h*)(zioA + lm*64 + off) = gA;
    *(v4h*)(zioB + lm*64 + off) = gB;
  }
}

__device__ __forceinline__ void gacc2(v4f& aGA, v4f& aGB,
    const _Float16* __restrict__ WxTbase,
    const _Float16* ZA, const _Float16* ZB, int lm, int q)
{
  const int rs = lm & 7;
#pragma unroll
  for (int kt = 0; kt < 2; ++kt){
    const int sw = (((kt*4 + q) ^ rs) << 3);
    v8h A  = *(const v8h*)(WxTbase + lm*64 + kt*32 + q*8);
    v8h BA = *(const v8h*)(ZA + lm*64 + sw);
    v8h BB = *(const v8h*)(ZB + lm*64 + sw);
    aGA = __builtin_amdgcn_mfma_f32_16x16x32_f16(A, BA, aGA, 0,0,0);
    aGB = __builtin_amdgcn_mfma_f32_16x16x32_f16(A, BB, aGB, 0,0,0);
  }
}

// ================= merged kernel: fhat -> ff(regs) -> vnet -> combine =================
__global__ __launch_bounds__(512, 4) void fused_kernel(
  const float* __restrict__ X, const float* __restrict__ Xst,
  const float* __restrict__ Vfx,
  const float* __restrict__ f1b, const float* __restrict__ f2b,
  const float* __restrict__ f3b, const float* __restrict__ f4b,
  const float* __restrict__ f5b, const float* __restrict__ ffb,
  float* __restrict__ out)
{
  __shared__ __align__(16) char smem[65536];   // fhat H 256x128 | vnet 8x8KB/wave
  _Float16* const H = (_Float16*)smem;

  const int b  = blockIdx.x;
  const int t  = threadIdx.x;
  const int w  = t >> 6;     // 0..7
  const int l  = t & 63;
  const int lm = l & 15;
  const int q  = l >> 4;
  const int rs = lm & 7;
  const int row0 = b*256 + w*32;

  const int r0 = row0 + lm;
  const int r1 = row0 + 16 + lm;
  const int rc0 = r0 < NPTS ? r0 : NPTS-1;
  const int rc1 = r1 < NPTS ? r1 : NPTS-1;
  const float2 x0 = *(const float2*)(X + rc0*2);
  const float2 x1 = *(const float2*)(X + rc1*2);

  // ========== fhat phase ==========
  // ---- f1 via MFMA: A = f1w padded to K=32, B = x (q==0 lanes k=0,1) ----
  {
    v8h Bx0 = (v8h){(_Float16)0.f,(_Float16)0.f,(_Float16)0.f,(_Float16)0.f,
                    (_Float16)0.f,(_Float16)0.f,(_Float16)0.f,(_Float16)0.f};
    v8h Bx1 = Bx0;
    if (q == 0){
      Bx0[0] = (_Float16)x0.x; Bx0[1] = (_Float16)x0.y;
      Bx1[0] = (_Float16)x1.x; Bx1[1] = (_Float16)x1.y;
    }
#pragma unroll
    for (int mt = 0; mt < 8; ++mt){
      const int o0 = mt*16 + q*4;
      const v4f bv = *(const v4f*)(f1b + o0);
      v8h A = *(const v8h*)(g_w16 + OFF_F1P + (mt*16 + lm)*32 + q*8);
      v4f a0 = __builtin_amdgcn_mfma_f32_16x16x32_f16(A, Bx0, bv, 0,0,0);
      v4f a1 = __builtin_amdgcn_mfma_f32_16x16x32_f16(A, Bx1, bv, 0,0,0);
      const int coff = (((o0 >> 3) ^ lm) << 3) + (o0 & 7);
      v4h h0, h1;
      *(v2h*)&h0       = lrelu_pk(a0[0], a0[1]);
      *((v2h*)&h0 + 1) = lrelu_pk(a0[2], a0[3]);
      *(v2h*)&h1       = lrelu_pk(a1[0], a1[1]);
      *((v2h*)&h1 + 1) = lrelu_pk(a1[2], a1[3]);
      *(v4h*)(H + (w*32 + lm)*128 + coff)      = h0;
      *(v4h*)(H + (w*32 + 16 + lm)*128 + coff) = h1;
    }
  }
  BAR_LDS();

  fh_layer(H, g_w16 + OFF_FW,         f2b, w, lm, q);
  fh_layer(H, g_w16 + OFF_FW + 16384, f3b, w, lm, q);
  fh_layer(H, g_w16 + OFF_FW + 32768, f4b, w, lm, q);
  fh_layer(H, g_w16 + OFF_FW + 49152, f5b, w, lm, q);

  // ---- ff via MFMA on the wave's OWN rows (w*32..w*32+31) ----
  float fhA0, fhA1, fhB0, fhB1;
  {
    v4f a0 = (v4f){0.f,0.f,0.f,0.f};
    v4f a1 = (v4f){0.f,0.f,0.f,0.f};
#pragma unroll
    for (int kt = 0; kt < 4; ++kt){
      const int sw = ((kt*4 + q) ^ lm) << 3;
      v8h A  = *(const v8h*)(g_w16 + OFF_FFW + lm*128 + kt*32 + q*8);
      v8h B0 = *(const v8h*)(H + (w*32 + lm)*128 + sw);
      v8h B1 = *(const v8h*)(H + (w*32 + 16 + lm)*128 + sw);
      a0 = __builtin_amdgcn_mfma_f32_16x16x32_f16(A, B0, a0, 0,0,0);
      a1 = __builtin_amdgcn_mfma_f32_16x16x32_f16(A, B1, a1, 0,0,0);
    }
    const float fb0 = ffb[0], fb1 = ffb[1];
    fhA0 = a0[0] + fb0; fhA1 = a0[1] + fb1;
    fhB0 = a1[0] + fb0; fhB1 = a1[1] + fb1;
  }

  // ========== vnet phase (wave-local slice) ==========
  _Float16* const ZA2 = (_Float16*)(smem + w*8192);
  _Float16* const ZA3 = ZA2 + 1024;
  _Float16* const ZB2 = ZA2 + 2048;
  _Float16* const ZB3 = ZA2 + 3072;

  const float2 sA = *(const float2*)(Xst + rc0*2);
  const float2 sB = *(const float2*)(Xst + rc1*2);
  const float dA0 = x0.x - sA.x, dA1 = x0.y - sA.y;
  const float dB0 = x1.x - sB.x, dB1 = x1.y - sB.y;
  const float vfx0 = Vfx[0], vfx1 = Vfx[1];

  // d B-fragments for the Wx@d MFMA fold (q==0 lanes carry k=0,1)
  v8h BdA = (v8h){(_Float16)0.f,(_Float16)0.f,(_Float16)0.f,(_Float16)0.f,
                  (_Float16)0.f,(_Float16)0.f,(_Float16)0.f,(_Float16)0.f};
  v8h BdB = BdA;
  if (q == 0){
    BdA[0] = (_Float16)dA0; BdA[1] = (_Float16)dA1;
    BdB[0] = (_Float16)dB0; BdB[1] = (_Float16)dB1;
  }

  // fwd: z2 (z1 in registers, srelu'(a2) carried out), z3
  float sdA2[16], sdB2[16];
  vfwd2_l2(ZA2, ZB2, g_w16 + OFF_V2Z, g_w16 + OFF_V2XP, g_w16 + OFF_VL1T,
           BdA, BdB, dA0, dA1, dB0, dB1, sdA2, sdB2, lm, q);
  vfwd2(ZA2, ZA3, ZB2, ZB3, g_w16 + OFF_V3Z, g_w16 + OFF_V3XP,
        BdA, BdB, lm, q);

  // zf head for both (A row 0 = Vfz)
  float VVrA, sfA, VVrB, sfB;
  {
    v4f aSA = (v4f){0.f,0.f,0.f,0.f};
    v4f aSB = (v4f){0.f,0.f,0.f,0.f};
#pragma unroll
    for (int kt = 0; kt < 2; ++kt){
      const int sw = (((kt*4 + q) ^ rs) << 3);
      v8h A  = *(const v8h*)(g_w16 + OFF_VFZ + lm*64 + kt*32 + q*8);
      v8h BA = *(const v8h*)(ZA3 + lm*64 + sw);
      v8h BB = *(const v8h*)(ZB3 + lm*64 + sw);
      aSA = __builtin_amdgcn_mfma_f32_16x16x32_f16(A, BA, aSA, 0,0,0);
      aSB = __builtin_amdgcn_mfma_f32_16x16x32_f16(A, BB, aSB, 0,0,0);
    }
    const float afA = fmaf(vfx0, dA0, fmaf(vfx1, dA1, aSA[0]));
    const float zfA = srelu(afA);
    VVrA = srelu(zfA) + 0.01f * fmaf(dA0, dA0, dA1*dA1);
    sfA  = sreluD(zfA) * sreluD(afA);
    const float afB = fmaf(vfx0, dB0, fmaf(vfx1, dB1, aSB[0]));
    const float zfB = srelu(afB);
    VVrB = srelu(zfB) + 0.01f * fmaf(dB0, dB0, dB1*dB1);
    sfB  = sreluD(zfB) * sreluD(afB);
  }

  // u3 = Vfz * srelu'(a3) (sf deferred; in place over Z3)
#pragma unroll
  for (int cc = 0; cc < 2; ++cc){
    const int c = q*2 + cc;
    const int sw = ((c ^ rs) << 3);
    v8h vf = *(const v8h*)(g_w16 + OFF_VFZ + c*8);
    _Float16* pA = ZA3 + lm*64 + sw;
    _Float16* pB = ZB3 + lm*64 + sw;
    v8h zA = *(const v8h*)pA;
    v8h zB = *(const v8h*)pB;
    v8h uA, uB;
#pragma unroll
    for (int j2 = 0; j2 < 4; ++j2){
      float a0 = (float)vf[2*j2  ] * sreluD_from_z((float)zA[2*j2  ]);
      float a1 = (float)vf[2*j2+1] * sreluD_from_z((float)zA[2*j2+1]);
      float b0 = (float)vf[2*j2  ] * sreluD_from_z((float)zB[2*j2  ]);
      float b1 = (float)vf[2*j2+1] * sreluD_from_z((float)zB[2*j2+1]);
      ((v2h*)&uA)[j2] = cvt_pk(a0, a1);
      ((v2h*)&uB)[j2] = cvt_pk(b0, b1);
    }
    *(v8h*)pA = uA;
    *(v8h*)pB = uB;
  }

  // incremental gradV, interleaved with backward (arena reuse)
  v4f aGA = (v4f){0.f,0.f,0.f,0.f};
  v4f aGB = (v4f){0.f,0.f,0.f,0.f};

  gacc2(aGA, aGB, g_w16 + OFF_V3XT, ZA3, ZB3, lm, q);             // L3 (ga3=u3)
  vbwd2(ZA3, ZA2, ZB3, ZB2, g_w16 + OFF_V3ZT, sdA2, sdB2, lm, q); // ga2 -> Z2
  gacc2(aGA, aGB, g_w16 + OFF_V2XT, ZA2, ZB2, lm, q);             // L2
  vbwd2_l1(ZA2, ZB2, g_w16 + OFF_V2ZT, g_w16 + OFF_VL1T,
           dA0, dA1, dB0, dB1, lm, q);                            // ga1 -> Z2
  gacc2(aGA, aGB, g_w16 + OFF_VL1T, ZA2, ZB2, lm, q);             // L1

  const float g0A = fmaf(0.02f, dA0, sfA * (vfx0 + aGA[0]));
  const float g1A = fmaf(0.02f, dA1, sfA * (vfx1 + aGA[1]));
  const float g0B = fmaf(0.02f, dB0, sfB * (vfx0 + aGB[0]));
  const float g1B = fmaf(0.02f, dB1, sfB * (vfx1 + aGB[1]));

  // ========== combine in registers, store out ==========
  if (q == 0){
    if (r0 < NPTS){
      const float Vn  = fmaf(g0A, g0A, g1A*g1A);
      const float num = fmaf(0.1f, VVrA, fmaf(fhA0, g0A, fhA1*g1A));
      const float fm  = fmaxf(num, 0.f) / (Vn + 1e-10f);
      *(float2*)(out + r0*2) =
        make_float2(fmaf(-g0A, fm, fhA0), fmaf(-g1A, fm, fhA1));
    }
    if (r1 < NPTS){
      const float Vn  = fmaf(g0B, g0B, g1B*g1B);
      const float num = fmaf(0.1f, VVrB, fmaf(fhB0, g0B, fhB1*g1B));
      const float fm  = fmaxf(num, 0.f) / (Vn + 1e-10f);
      *(float2*)(out + r1*2) =
        make_float2(fmaf(-g0B, fm, fhB0), fmaf(-g1B, fm, fhB1));
    }
  }
}

extern "C" void kernel_launch(void* const* d_in, const int* in_sizes, int n_in,
                              void* d_out, int out_size, void* d_ws, size_t ws_size,
                              hipStream_t stream)
{
  (void)d_ws; (void)ws_size; (void)n_in; (void)in_sizes; (void)out_size;
  const float* X   = (const float*)d_in[0];
  const float* Xst = (const float*)d_in[1];
  const float* Vl1 = (const float*)d_in[2];
  const float* V2x = (const float*)d_in[3];
  const float* V2z = (const float*)d_in[4];
  const float* V3x = (const float*)d_in[5];
  const float* V3z = (const float*)d_in[6];
  const float* Vfx = (const float*)d_in[7];
  const float* Vfz = (const float*)d_in[8];
  const float* f1w = (const float*)d_in[9];
  const float* f1b = (const float*)d_in[10];
  const float* f2w = (const float*)d_in[11];
  const float* f2b = (const float*)d_in[12];
  const float* f3w = (const float*)d_in[13];
  const float* f3b = (const float*)d_in[14];
  const float* f4w = (const float*)d_in[15];
  const float* f4b = (const float*)d_in[16];
  const float* f5w = (const float*)d_in[17];
  const float* f5b = (const float*)d_in[18];
  const float* ffw = (const float*)d_in[19];
  const float* ffb = (const float*)d_in[20];

  prep_kernel<<<(W16_TOTAL + 255)/256, 256, 0, stream>>>(
      f2w, f3w, f4w, f5w, V2z, V3z, Vl1, V2x, V3x, Vfz, ffw, f1w);
  fused_kernel<<<FUSED_GRID, 512, 0, stream>>>(
      X, Xst, Vfx, f1b, f2b, f3b, f4b, f5b, ffb, (float*)d_out);
}